// Round 9
// baseline (982.493 us; speedup 1.0000x reference)
//
#include <hip/hip_runtime.h>
#include <hip/hip_bf16.h>
#include <math.h>

#define ISZ 256
#define KSEL 31       // keep top-(K+1) = 31
#define CAP 768       // per-row candidate buffer cap
#define NSAMP 128     // threshold-calibration samples
#define SSTR 78       // sample stride (127*78 = 9906 < 10000)
#define ZQ 2.15f      // target ~150 candidates/row
#define DELTA 0.008f  // health margin (>= 2x bf16-GEMM sim error)
#define EPSB 0.003f   // per-sim error bound for borderline window
// fallback-path constants (round-8 proven)
#define CMINF 64
#define CEXITF 192
#define NCANDF 256

typedef __attribute__((ext_vector_type(8))) short bf16x8;
typedef __attribute__((ext_vector_type(4))) float f32x4;

__device__ __forceinline__ double h64_of(float f, float w0, float w1) {
    return fmax((double)f * (double)w0, 0.0) * (double)w1;
}

// ---------------- shared: embedding ----------------
__global__ __launch_bounds__(256) void emb_kernel(const float* __restrict__ F,
                                                  const float* __restrict__ w0,
                                                  const float* __restrict__ w1,
                                                  __hip_bfloat16* __restrict__ Eb,
                                                  double* __restrict__ snorm,
                                                  int n) {
    int row = blockIdx.x;
    int t = threadIdx.x;
    float f = F[(size_t)row * ISZ + t];
    double h64 = h64_of(f, w0[t], w1[t]);
    double ss = h64 * h64;
#pragma unroll
    for (int off = 32; off; off >>= 1) ss += __shfl_down(ss, off);
    __shared__ double red[4];
    if ((t & 63) == 0) red[t >> 6] = ss;
    __syncthreads();
    double tot = red[0] + red[1] + red[2] + red[3];
    double s = fmax(sqrt(tot), 1e-12);
    if (t == 0) snorm[row] = s;
    Eb[(size_t)row * ISZ + t] = __float2bfloat16((float)(h64 / s));
}

__global__ void zero_cnt(int* cnt, int* cnt2, int n) {
    int i = blockIdx.x * 256 + threadIdx.x;
    if (i < n) { cnt[i] = 0; cnt2[i] = 0; }
}

// EbS[e][s] = Eb[samp(s)][e]  (transposed sample pack for coalesced prepass)
__global__ __launch_bounds__(256) void pack_samples(const __hip_bfloat16* __restrict__ Eb,
                                                    __hip_bfloat16* __restrict__ EbS, int n) {
    int s = blockIdx.x;      // 0..NSAMP-1
    int t = threadIdx.x;     // 0..255
    EbS[t * NSAMP + s] = Eb[(size_t)(s * SSTR) * ISZ + t];
}

// Per-row threshold: mean/sd over NSAMP sample sims, t0 = m + ZQ*sd.
__global__ __launch_bounds__(128) void prepass_t0(const __hip_bfloat16* __restrict__ Eb,
                                                  const __hip_bfloat16* __restrict__ EbS,
                                                  float* __restrict__ t0arr, int n) {
    __shared__ float hrow[ISZ];
    __shared__ float reda[2], redb[2];
    __shared__ int redc[2];
    int row = blockIdx.x, t = threadIdx.x;
    hrow[t] = __bfloat162float(Eb[(size_t)row * ISZ + t]);
    hrow[t + 128] = __bfloat162float(Eb[(size_t)row * ISZ + t + 128]);
    __syncthreads();
    int samp = t * SSTR;
    float acc = 0.0f;
    for (int e = 0; e < ISZ; ++e)
        acc += hrow[e] * __bfloat162float(EbS[e * NSAMP + t]);
    bool ex = (samp == row);
    float a = ex ? 0.0f : acc, a2 = ex ? 0.0f : acc * acc;
    int c = ex ? 0 : 1;
#pragma unroll
    for (int off = 32; off; off >>= 1) {
        a += __shfl_down(a, off);
        a2 += __shfl_down(a2, off);
        c += __shfl_down(c, off);
    }
    int w = t >> 6;
    if ((t & 63) == 0) { reda[w] = a; redb[w] = a2; redc[w] = c; }
    __syncthreads();
    if (t == 0) {
        float S = reda[0] + reda[1], S2 = redb[0] + redb[1];
        int C = redc[0] + redc[1];
        float mean = S / (float)C;
        float var = fmaxf(S2 / (float)C - mean * mean, 1e-8f);
        t0arr[row] = mean + ZQ * sqrtf(var);
    }
}

// Fused GEMM + candidate collection. No sim-matrix store. Symmetric cull with
// dual-direction append. cnt2 counts sims >= t0+DELTA (health certificate).
__global__ __launch_bounds__(256) void gemm_collect(const __hip_bfloat16* __restrict__ Eb,
                                                    const float* __restrict__ t0arr,
                                                    int* __restrict__ cnt,
                                                    int* __restrict__ cnt2,
                                                    int2* __restrict__ buf, int n) {
    int bx = blockIdx.x, by = blockIdx.y;
    if (bx < by) return;
    int row0 = by * 128, col0 = bx * 128;
    int tid = threadIdx.x, lane = tid & 63, wid = tid >> 6;
    int wr = wid >> 1, wc = wid & 1;
    int rbase = row0 + wr * 64 + (lane & 15);
    int cbase = col0 + wc * 64 + (lane & 15);
    int kg2 = ((lane >> 4) * 8) * 2;
    const char* Ep = (const char*)Eb;
    unsigned aoff[4], boff[4];
#pragma unroll
    for (int i = 0; i < 4; ++i) {
        aoff[i] = (unsigned)min(rbase + i * 16, n - 1) * (ISZ * 2) + kg2;
        boff[i] = (unsigned)min(cbase + i * 16, n - 1) * (ISZ * 2) + kg2;
    }
    f32x4 acc[4][4] = {};
#pragma unroll
    for (int kt = 0; kt < ISZ; kt += 32) {
        bf16x8 a[4], b[4];
#pragma unroll
        for (int i = 0; i < 4; ++i) a[i] = *(const bf16x8*)(Ep + aoff[i] + kt * 2);
#pragma unroll
        for (int j = 0; j < 4; ++j) b[j] = *(const bf16x8*)(Ep + boff[j] + kt * 2);
#pragma unroll
        for (int i = 0; i < 4; ++i)
#pragma unroll
            for (int j = 0; j < 4; ++j)
                acc[i][j] = __builtin_amdgcn_mfma_f32_16x16x32_bf16(a[i], b[j], acc[i][j], 0, 0, 0);
    }
    int orow = row0 + wr * 64 + (lane >> 4) * 4;
    int ocol = col0 + wc * 64 + (lane & 15);
    bool mir = (bx > by);
    float tcol[4];
#pragma unroll
    for (int j = 0; j < 4; ++j) {
        int cc = ocol + j * 16;
        tcol[j] = (mir && cc < n) ? t0arr[cc] : 3e38f;   // 3e38 => never appends
    }
#pragma unroll
    for (int i = 0; i < 4; ++i)
#pragma unroll
        for (int r = 0; r < 4; ++r) {
            int rr = orow + i * 16 + r;
            if (rr >= n) continue;
            float t0r = t0arr[rr];
#pragma unroll
            for (int j = 0; j < 4; ++j) {
                int cc = ocol + j * 16;
                if (cc >= n) continue;
                float val = acc[i][j][r];
                if (val >= t0r) {
                    int pos = atomicAdd(&cnt[rr], 1);
                    if (pos < CAP) buf[(size_t)rr * CAP + pos] = make_int2(cc, __float_as_int(val));
                    if (val >= t0r + DELTA) atomicAdd(&cnt2[rr], 1);
                }
                if (val >= tcol[j]) {
                    int pos = atomicAdd(&cnt[cc], 1);
                    if (pos < CAP) buf[(size_t)cc * CAP + pos] = make_int2(rr, __float_as_int(val));
                    if (val >= tcol[j] + DELTA) atomicAdd(&cnt2[cc], 1);
                }
            }
        }
}

// Deterministic rebuild of unhealthy rows (expected ~0 rows): brute-force
// per-col dots, round-8-style register bisection, collect with margin.
__global__ __launch_bounds__(256) void cleanup(const __hip_bfloat16* __restrict__ Eb,
                                               int* __restrict__ cnt,
                                               int* __restrict__ cnt2,
                                               int2* __restrict__ buf, int n) {
    int row = blockIdx.x;
    if (cnt[row] <= CAP && cnt2[row] >= KSEL) return;   // healthy
    __shared__ float hrow[ISZ];
    __shared__ int redi[4];
    __shared__ int lcnt;
    int tid = threadIdx.x, lane = tid & 63, wid = tid >> 6;
    hrow[tid] = __bfloat162float(Eb[(size_t)row * ISZ + tid]);
    if (tid == 0) lcnt = 0;
    __syncthreads();
    float v[40];
    for (int s = 0; s < 40; ++s) {
        int col = tid + 256 * s;
        if (col < n) {
            float acc = 0.0f;
            for (int e = 0; e < ISZ; ++e)
                acc += hrow[e] * __bfloat162float(Eb[(size_t)col * ISZ + e]);
            v[s] = acc;
        } else v[s] = -1e30f;
    }
    auto blockcount = [&](float tt) -> int {
        int c = 0;
#pragma unroll
        for (int q = 0; q < 40; ++q) c += (v[q] >= tt) ? 1 : 0;
#pragma unroll
        for (int off = 32; off; off >>= 1) c += __shfl_down(c, off);
        if (lane == 0) redi[wid] = c;
        __syncthreads();
        int tot = redi[0] + redi[1] + redi[2] + redi[3];
        __syncthreads();
        return tot;
    };
    float lo = 0.0f, hi = 1.01f, thr = 0.0f;
    bool found = false;
    for (int it = 0; it < 30 && !found; ++it) {
        float mid = 0.5f * (lo + hi);
        int c = blockcount(mid);
        if (c >= 64 && c <= 600) { thr = mid; found = true; }
        else if (c >= 64) lo = mid;
        else hi = mid;
    }
    if (!found) thr = lo;
    thr -= DELTA;   // inclusion margin
    for (int s = 0; s < 40; ++s) {
        if (v[s] >= thr) {
            int pos = atomicAdd(&lcnt, 1);
            if (pos < CAP)
                buf[(size_t)row * CAP + pos] = make_int2(tid + 256 * s, __float_as_int(v[s]));
        }
    }
    __syncthreads();
    if (tid == 0) { cnt[row] = min(lcnt, CAP); cnt2[row] = KSEL; }
}

// Per row: 31st-largest stored sim; definite-ins patched with stored value;
// borderline window recomputed fp64-from-inputs and exactly ranked (stable
// lowest-index ties). Zeros + patches fully rewrite the output each call.
__global__ __launch_bounds__(256) void refine_out(float* __restrict__ OUT,
                                                  const int2* __restrict__ buf,
                                                  const int* __restrict__ cnt,
                                                  const float* __restrict__ F,
                                                  const float* __restrict__ W0,
                                                  const float* __restrict__ W1,
                                                  const double* __restrict__ snorm,
                                                  int n) {
    __shared__ int cidx[CAP];
    __shared__ float csim[CAP];
    __shared__ double cval[CAP];
    __shared__ int blist[CAP];
    __shared__ float s31s;
    __shared__ int nhi_s, nbl_s;
    int row = blockIdx.x, tid = threadIdx.x, lane = tid & 63, wid = tid >> 6;
    int m = cnt[row]; if (m > CAP) m = CAP;
    for (int c = tid; c < m; c += 256) {
        int2 p = buf[(size_t)row * CAP + c];
        cidx[c] = p.x;
        csim[c] = __int_as_float(p.y);
    }
    if (tid == 0) { nhi_s = 0; nbl_s = 0; }
    __syncthreads();
    // 31st-largest stored sim (unique rank via index tie-break)
    for (int c = tid; c < m; c += 256) {
        float mys = csim[c]; int myi = cidx[c]; int r = 0;
        for (int j = 0; j < m; ++j) {
            float vj = csim[j];
            r += (vj > mys || (vj == mys && cidx[j] < myi)) ? 1 : 0;
        }
        if (r == KSEL - 1) s31s = mys;
    }
    __syncthreads();
    float s31 = s31s;
    float W = 2.0f * EPSB;
    for (int c = tid; c < m; c += 256) {
        float sc = csim[c];
        if (sc > s31 + W) atomicAdd(&nhi_s, 1);
        else if (sc >= s31 - W) { int p = atomicAdd(&nbl_s, 1); blist[p] = c; }
    }
    __syncthreads();
    int nhi = nhi_s, nbl = nbl_s, kneed = KSEL - nhi;
    // fp64 recompute of borderline candidates only (2-way ILP)
    double hr[4]; float w0e[4], w1e[4];
#pragma unroll
    for (int r = 0; r < 4; ++r) {
        int e = lane + 64 * r;
        w0e[r] = W0[e]; w1e[r] = W1[e];
        hr[r] = h64_of(F[(size_t)row * ISZ + e], w0e[r], w1e[r]);
    }
    double srow = snorm[row];
    for (int c = wid * 2; c < nbl; c += 8) {
        int s1 = blist[c];
        bool ok2 = (c + 1 < nbl);
        int s2 = ok2 ? blist[c + 1] : s1;
        int j1 = cidx[s1], j2 = cidx[s2];
        double a1 = 0.0, a2 = 0.0;
#pragma unroll
        for (int r = 0; r < 4; ++r) {
            int e = lane + 64 * r;
            a1 += hr[r] * h64_of(F[(size_t)j1 * ISZ + e], w0e[r], w1e[r]);
            a2 += hr[r] * h64_of(F[(size_t)j2 * ISZ + e], w0e[r], w1e[r]);
        }
#pragma unroll
        for (int off = 32; off; off >>= 1) {
            a1 += __shfl_down(a1, off);
            a2 += __shfl_down(a2, off);
        }
        if (lane == 0) {
            cval[s1] = a1 / (srow * snorm[j1]);
            if (ok2) cval[s2] = a2 / (srow * snorm[j2]);
        }
    }
    __syncthreads();
    // zero row, then patch
    float* outp = OUT + (size_t)row * n;
    float4 z4 = make_float4(0.f, 0.f, 0.f, 0.f);
    for (int e = 4 * tid; e < n; e += 1024) *(float4*)(outp + e) = z4;
    __syncthreads();
    for (int c = tid; c < m; c += 256)
        if (csim[c] > s31 + W) outp[cidx[c]] = fmaxf(csim[c], 0.0f);
    for (int b = tid; b < nbl; b += 256) {
        int slot = blist[b];
        double vv = cval[slot]; int myi = cidx[slot]; int r2 = 0;
        for (int j = 0; j < nbl; ++j) {
            int sj = blist[j]; double vj = cval[sj];
            r2 += (vj > vv || (vj == vv && cidx[sj] < myi)) ? 1 : 0;
        }
        if (r2 < kneed) outp[myi] = (float)fmax(vv, 0.0);
    }
}

// ---------------- round-8 proven fallback (small-ws path) ----------------
__global__ __launch_bounds__(256) void gemm_store_fb(const __hip_bfloat16* __restrict__ Eb,
                                                     float* __restrict__ S, int n) {
    int bx = blockIdx.x, by = blockIdx.y;
    int row0 = by * 128, col0 = bx * 128;
    int tid = threadIdx.x, lane = tid & 63, wid = tid >> 6;
    int wr = wid >> 1, wc = wid & 1;
    int rbase = row0 + wr * 64 + (lane & 15);
    int cbase = col0 + wc * 64 + (lane & 15);
    int kg2 = ((lane >> 4) * 8) * 2;
    const char* Ep = (const char*)Eb;
    unsigned aoff[4], boff[4];
#pragma unroll
    for (int i = 0; i < 4; ++i) {
        aoff[i] = (unsigned)min(rbase + i * 16, n - 1) * (ISZ * 2) + kg2;
        boff[i] = (unsigned)min(cbase + i * 16, n - 1) * (ISZ * 2) + kg2;
    }
    f32x4 acc[4][4] = {};
#pragma unroll
    for (int kt = 0; kt < ISZ; kt += 32) {
        bf16x8 a[4], b[4];
#pragma unroll
        for (int i = 0; i < 4; ++i) a[i] = *(const bf16x8*)(Ep + aoff[i] + kt * 2);
#pragma unroll
        for (int j = 0; j < 4; ++j) b[j] = *(const bf16x8*)(Ep + boff[j] + kt * 2);
#pragma unroll
        for (int i = 0; i < 4; ++i)
#pragma unroll
            for (int j = 0; j < 4; ++j)
                acc[i][j] = __builtin_amdgcn_mfma_f32_16x16x32_bf16(a[i], b[j], acc[i][j], 0, 0, 0);
    }
    int orow = row0 + wr * 64 + (lane >> 4) * 4;
    int ocol = col0 + wc * 64 + (lane & 15);
#pragma unroll
    for (int i = 0; i < 4; ++i)
#pragma unroll
        for (int r = 0; r < 4; ++r) {
            int rr = orow + i * 16 + r;
            if (rr < n) {
#pragma unroll
                for (int j = 0; j < 4; ++j) {
                    int cc = ocol + j * 16;
                    if (cc < n) S[(size_t)rr * n + cc] = acc[i][j][r];
                }
            }
        }
}

__global__ __launch_bounds__(256) void topk_fb(float* __restrict__ C,
                                               const float* __restrict__ F,
                                               const float* __restrict__ W0,
                                               const float* __restrict__ W1,
                                               const double* __restrict__ snorm,
                                               int n) {
    __shared__ unsigned flags[320];
    __shared__ int redi[4];
    __shared__ int cand_idx[NCANDF];
    __shared__ double cand_val[NCANDF];
    __shared__ int ncand;
    int row = blockIdx.x;
    int tid = threadIdx.x;
    int lane = tid & 63, wid = tid >> 6;
    float* rowp = C + (size_t)row * n;
    float v[40];
#pragma unroll
    for (int s = 0; s < 10; ++s) {
        int e = 4 * tid + 1024 * s;
        if (e < n) {
            float4 w = *(const float4*)(rowp + e);
            v[s * 4 + 0] = w.x; v[s * 4 + 1] = w.y;
            v[s * 4 + 2] = w.z; v[s * 4 + 3] = w.w;
        } else {
#pragma unroll
            for (int q = 0; q < 4; ++q) v[s * 4 + q] = -1e30f;
        }
    }
    for (int q = tid; q < 320; q += 256) flags[q] = 0;
    if (tid == 0) ncand = 0;
    __syncthreads();
    auto blockcount = [&](float t) -> int {
        int c = 0;
#pragma unroll
        for (int q = 0; q < 40; ++q) c += (v[q] >= t) ? 1 : 0;
#pragma unroll
        for (int off = 32; off; off >>= 1) c += __shfl_down(c, off);
        if (lane == 0) redi[wid] = c;
        __syncthreads();
        int tot = redi[0] + redi[1] + redi[2] + redi[3];
        __syncthreads();
        return tot;
    };
    float lo = 0.0f, hi = 0.75f, thr = 0.0f;
    bool found = false;
    for (int it = 0; it < 30 && !found; ++it) {
        float mid = 0.5f * (lo + hi);
        int c = blockcount(mid);
        if (c >= CMINF && c <= CEXITF) { thr = mid; found = true; }
        else if (c >= CMINF) lo = mid;
        else hi = mid;
    }
    if (!found) thr = lo;
#pragma unroll
    for (int s = 0; s < 10; ++s) {
        int e = 4 * tid + 1024 * s;
#pragma unroll
        for (int j = 0; j < 4; ++j) {
            if (v[s * 4 + j] >= thr) {
                int pos = atomicAdd(&ncand, 1);
                if (pos < NCANDF) cand_idx[pos] = e + j;
            }
        }
    }
    __syncthreads();
    int m = min(ncand, NCANDF);
    double hr[4]; float w0e[4], w1e[4];
#pragma unroll
    for (int r = 0; r < 4; ++r) {
        int e = lane + 64 * r;
        w0e[r] = W0[e]; w1e[r] = W1[e];
        hr[r] = h64_of(F[(size_t)row * ISZ + e], w0e[r], w1e[r]);
    }
    double srow = snorm[row];
    for (int c = wid * 2; c < m; c += 8) {
        int j1 = cand_idx[c];
        int c2ok = (c + 1 < m);
        int j2 = c2ok ? cand_idx[c + 1] : j1;
        double a1 = 0.0, a2 = 0.0;
#pragma unroll
        for (int r = 0; r < 4; ++r) {
            int e = lane + 64 * r;
            a1 += hr[r] * h64_of(F[(size_t)j1 * ISZ + e], w0e[r], w1e[r]);
            a2 += hr[r] * h64_of(F[(size_t)j2 * ISZ + e], w0e[r], w1e[r]);
        }
#pragma unroll
        for (int off = 32; off; off >>= 1) { a1 += __shfl_down(a1, off); a2 += __shfl_down(a2, off); }
        if (lane == 0) {
            cand_val[c] = a1 / (srow * snorm[j1]);
            if (c2ok) cand_val[c + 1] = a2 / (srow * snorm[j2]);
        }
    }
    __syncthreads();
    int myrank = KSEL;
    if (tid < m) {
        double vv = cand_val[tid]; int idx = cand_idx[tid]; int rank = 0;
        for (int j2 = 0; j2 < m; ++j2) {
            double vj = cand_val[j2];
            rank += (vj > vv || (vj == vv && cand_idx[j2] < idx)) ? 1 : 0;
        }
        myrank = rank;
        if (rank < KSEL) atomicOr(&flags[idx >> 5], 1u << (idx & 31));
    }
    __syncthreads();
#pragma unroll
    for (int s = 0; s < 10; ++s) {
        int e = 4 * tid + 1024 * s;
        if (e >= n) continue;
        float vals[4] = {v[s * 4], v[s * 4 + 1], v[s * 4 + 2], v[s * 4 + 3]};
        float o[4];
#pragma unroll
        for (int j = 0; j < 4; ++j) {
            int q = e + j;
            bool keep = (flags[q >> 5] >> (q & 31)) & 1u;
            o[j] = (keep && vals[j] > 0.0f) ? vals[j] : 0.0f;
        }
        *(float4*)(rowp + e) = make_float4(o[0], o[1], o[2], o[3]);
    }
    __syncthreads();
    if (tid < m && myrank < KSEL) rowp[cand_idx[tid]] = (float)fmax(cand_val[tid], 0.0);
}

extern "C" void kernel_launch(void* const* d_in, const int* in_sizes, int n_in,
                              void* d_out, int out_size, void* d_ws, size_t ws_size,
                              hipStream_t stream) {
    const float* F  = (const float*)d_in[0];
    const float* w0 = (const float*)d_in[1];
    const float* w1 = (const float*)d_in[2];
    float* out = (float*)d_out;
    int isz = in_sizes[1];           // 256
    int n = in_sizes[0] / isz;       // 10000

    char* ws = (char*)d_ws;
    // layout: snorm | buf(int2) | Ebf | EbS | t0 | cnt | cnt2
    size_t o_snorm = 0;
    size_t o_buf   = o_snorm + (size_t)n * 8;
    size_t o_ebf   = o_buf + (size_t)n * CAP * 8;
    size_t o_ebs   = o_ebf + (size_t)n * ISZ * 2;
    size_t o_t0    = o_ebs + (size_t)ISZ * NSAMP * 2;
    size_t o_cnt   = o_t0 + (size_t)n * 4;
    size_t o_cnt2  = o_cnt + (size_t)n * 4;
    size_t need    = o_cnt2 + (size_t)n * 4;

    double* snorm = (double*)(ws + o_snorm);
    __hip_bfloat16* Ebf = (__hip_bfloat16*)(ws + o_ebf);

    int nt = (n + 127) / 128;
    if (ws_size >= need) {
        int2* buf = (int2*)(ws + o_buf);
        __hip_bfloat16* EbS = (__hip_bfloat16*)(ws + o_ebs);
        float* t0arr = (float*)(ws + o_t0);
        int* cnt = (int*)(ws + o_cnt);
        int* cnt2 = (int*)(ws + o_cnt2);

        zero_cnt<<<(n + 255) / 256, 256, 0, stream>>>(cnt, cnt2, n);
        emb_kernel<<<n, 256, 0, stream>>>(F, w0, w1, Ebf, snorm, n);
        pack_samples<<<NSAMP, 256, 0, stream>>>(Ebf, EbS, n);
        prepass_t0<<<n, 128, 0, stream>>>(Ebf, EbS, t0arr, n);
        gemm_collect<<<dim3(nt, nt), 256, 0, stream>>>(Ebf, t0arr, cnt, cnt2, buf, n);
        cleanup<<<n, 256, 0, stream>>>(Ebf, cnt, cnt2, buf, n);
        refine_out<<<n, 256, 0, stream>>>(out, buf, cnt, F, w0, w1, snorm, n);
    } else {
        // round-8 proven fallback: sim matrix in d_out
        emb_kernel<<<n, 256, 0, stream>>>(F, w0, w1, Ebf, snorm, n);
        gemm_store_fb<<<dim3(nt, nt), 256, 0, stream>>>(Ebf, out, n);
        topk_fb<<<n, 256, 0, stream>>>(out, F, w0, w1, snorm, n);
    }
}

// Round 10
// 877.555 us; speedup vs baseline: 1.1196x; 1.1196x over previous
//
#include <hip/hip_runtime.h>
#include <hip/hip_bf16.h>
#include <math.h>

#define ISZ 256
#define KSEL 31       // keep top-(K+1) = 31
#define CAP 768       // candidate cap
#define NSAMP 128     // calibration samples
#define SSTR 78       // sample stride (127*78 = 9906 < 10000)
#define ZQ 2.0f       // t0 = mean + ZQ*sd  (~230 candidates/row)

typedef __attribute__((ext_vector_type(8))) short bf16x8;
typedef __attribute__((ext_vector_type(4))) float f32x4;

__device__ __forceinline__ double h64_of(float f, float w0, float w1) {
    return fmax((double)f * (double)w0, 0.0) * (double)w1;
}
__device__ __forceinline__ float bf2f(unsigned short u) {
    return __uint_as_float(((unsigned)u) << 16);
}
template <typename ST> __device__ __forceinline__ ST to_st(float v);
template <> __device__ __forceinline__ float to_st<float>(float v) { return v; }
template <> __device__ __forceinline__ __hip_bfloat16 to_st<__hip_bfloat16>(float v) {
    return __float2bfloat16(v);
}

// ---------------- embedding ----------------
__global__ __launch_bounds__(256) void emb_kernel(const float* __restrict__ F,
                                                  const float* __restrict__ w0,
                                                  const float* __restrict__ w1,
                                                  __hip_bfloat16* __restrict__ Eb,
                                                  double* __restrict__ snorm,
                                                  int n) {
    int row = blockIdx.x;
    int t = threadIdx.x;
    float f = F[(size_t)row * ISZ + t];
    double h64 = h64_of(f, w0[t], w1[t]);
    double ss = h64 * h64;
#pragma unroll
    for (int off = 32; off; off >>= 1) ss += __shfl_down(ss, off);
    __shared__ double red[4];
    if ((t & 63) == 0) red[t >> 6] = ss;
    __syncthreads();
    double tot = red[0] + red[1] + red[2] + red[3];
    double s = fmax(sqrt(tot), 1e-12);
    if (t == 0) snorm[row] = s;
    Eb[(size_t)row * ISZ + t] = __float2bfloat16((float)(h64 / s));
}

// EbS[e][s] = Eb[samp(s)][e]  (transposed sample pack)
__global__ __launch_bounds__(256) void pack_samples(const __hip_bfloat16* __restrict__ Eb,
                                                    __hip_bfloat16* __restrict__ EbS, int n) {
    int s = blockIdx.x;
    int t = threadIdx.x;
    EbS[t * NSAMP + s] = Eb[(size_t)(s * SSTR) * ISZ + t];
}

// Per-row threshold t0 = mean + ZQ*sd over NSAMP sample sims.
__global__ __launch_bounds__(128) void prepass_t0(const __hip_bfloat16* __restrict__ Eb,
                                                  const __hip_bfloat16* __restrict__ EbS,
                                                  float* __restrict__ t0arr, int n) {
    __shared__ float hrow[ISZ];
    __shared__ float reda[2], redb[2];
    __shared__ int redc[2];
    int row = blockIdx.x, t = threadIdx.x;
    hrow[t] = __bfloat162float(Eb[(size_t)row * ISZ + t]);
    hrow[t + 128] = __bfloat162float(Eb[(size_t)row * ISZ + t + 128]);
    __syncthreads();
    int samp = t * SSTR;
    float acc = 0.0f;
    for (int e = 0; e < ISZ; ++e)
        acc += hrow[e] * __bfloat162float(EbS[e * NSAMP + t]);
    bool ex = (samp == row);
    float a = ex ? 0.0f : acc, a2 = ex ? 0.0f : acc * acc;
    int c = ex ? 0 : 1;
#pragma unroll
    for (int off = 32; off; off >>= 1) {
        a += __shfl_down(a, off);
        a2 += __shfl_down(a2, off);
        c += __shfl_down(c, off);
    }
    int w = t >> 6;
    if ((t & 63) == 0) { reda[w] = a; redb[w] = a2; redc[w] = c; }
    __syncthreads();
    if (t == 0) {
        float S = reda[0] + reda[1], S2 = redb[0] + redb[1];
        int C = redc[0] + redc[1];
        float mean = S / (float)C;
        float var = fmaxf(S2 / (float)C - mean * mean, 1e-8f);
        t0arr[row] = mean + ZQ * sqrtf(var);
    }
}

// S = Eb*Eb^T via MFMA 16x16x32 bf16, ST output. Round-8 proven structure.
template <typename ST>
__global__ __launch_bounds__(256) void gemm_st(const __hip_bfloat16* __restrict__ Eb,
                                               ST* __restrict__ S, int n) {
    int bx = blockIdx.x, by = blockIdx.y;
    int row0 = by * 128, col0 = bx * 128;
    int tid = threadIdx.x, lane = tid & 63, wid = tid >> 6;
    int wr = wid >> 1, wc = wid & 1;
    int rbase = row0 + wr * 64 + (lane & 15);
    int cbase = col0 + wc * 64 + (lane & 15);
    int kg2 = ((lane >> 4) * 8) * 2;
    const char* Ep = (const char*)Eb;
    unsigned aoff[4], boff[4];
#pragma unroll
    for (int i = 0; i < 4; ++i) {
        aoff[i] = (unsigned)min(rbase + i * 16, n - 1) * (ISZ * 2) + kg2;
        boff[i] = (unsigned)min(cbase + i * 16, n - 1) * (ISZ * 2) + kg2;
    }
    f32x4 acc[4][4] = {};
#pragma unroll
    for (int kt = 0; kt < ISZ; kt += 32) {
        bf16x8 a[4], b[4];
#pragma unroll
        for (int i = 0; i < 4; ++i) a[i] = *(const bf16x8*)(Ep + aoff[i] + kt * 2);
#pragma unroll
        for (int j = 0; j < 4; ++j) b[j] = *(const bf16x8*)(Ep + boff[j] + kt * 2);
#pragma unroll
        for (int i = 0; i < 4; ++i)
#pragma unroll
            for (int j = 0; j < 4; ++j)
                acc[i][j] = __builtin_amdgcn_mfma_f32_16x16x32_bf16(a[i], b[j], acc[i][j], 0, 0, 0);
    }
    int orow = row0 + wr * 64 + (lane >> 4) * 4;
    int ocol = col0 + wc * 64 + (lane & 15);
#pragma unroll
    for (int i = 0; i < 4; ++i)
#pragma unroll
        for (int r = 0; r < 4; ++r) {
            int rr = orow + i * 16 + r;
            if (rr < n) {
#pragma unroll
                for (int j = 0; j < 4; ++j) {
                    int cc = ocol + j * 16;
                    if (cc < n) S[(size_t)rr * n + cc] = to_st<ST>(acc[i][j][r]);
                }
            }
        }
}

// Per-row selection. Single streaming collect pass at precomputed t0;
// certificate-checked (fallback: streaming bisection). Stored-sim ranking
// finds s31; only |sim-s31|<=EPS2 get fp64 recompute; exact stable top-31.
// NOTE: SIM may alias OUT (fp32 in-place path) -> no __restrict__ on them.
template <typename ST>
__global__ __launch_bounds__(256) void topk_sel(const ST* SIM, float* OUT,
                                                const float* __restrict__ F,
                                                const float* __restrict__ W0,
                                                const float* __restrict__ W1,
                                                const double* __restrict__ snorm,
                                                const float* __restrict__ t0arr,
                                                int n) {
    constexpr bool BFS = (sizeof(ST) == 2);
    const float EPS2 = BFS ? 0.016f : 0.012f;   // >= 2x |stored - true| bound
    __shared__ int cidx[CAP];
    __shared__ float csim[CAP];
    __shared__ int blist[CAP];
    __shared__ double cval[CAP];
    __shared__ int redi[4];
    __shared__ int ncand_s, c2_s, nhi_s, nbl_s;
    __shared__ float s31_s;
    int row = blockIdx.x, tid = threadIdx.x, lane = tid & 63, wid = tid >> 6;
    const float t0 = t0arr[row];
    const ST* simrow = SIM + (size_t)row * n;
    if (tid == 0) { ncand_s = 0; c2_s = 0; nhi_s = 0; nbl_s = 0; }
    __syncthreads();

    // ---- pass 1: stream row, collect >= t0 ----
    if constexpr (BFS) {
        const unsigned short* sr = (const unsigned short*)simrow;
        for (int e = 8 * tid; e < n; e += 2048) {
            if (e + 7 < n) {
                uint4 w = *(const uint4*)(sr + e);
                unsigned wa[4] = {w.x, w.y, w.z, w.w};
#pragma unroll
                for (int q = 0; q < 4; ++q) {
                    float v0 = bf2f((unsigned short)(wa[q] & 0xFFFF));
                    float v1 = bf2f((unsigned short)(wa[q] >> 16));
                    if (v0 >= t0) { int p = atomicAdd(&ncand_s, 1); if (p < CAP) { cidx[p] = e + 2 * q; csim[p] = v0; } }
                    if (v1 >= t0) { int p = atomicAdd(&ncand_s, 1); if (p < CAP) { cidx[p] = e + 2 * q + 1; csim[p] = v1; } }
                }
            } else {
                for (int q = e; q < n; ++q) {
                    float v0 = bf2f(sr[q]);
                    if (v0 >= t0) { int p = atomicAdd(&ncand_s, 1); if (p < CAP) { cidx[p] = q; csim[p] = v0; } }
                }
            }
        }
    } else {
        const float* sr = (const float*)simrow;
        for (int e = 4 * tid; e < n; e += 1024) {
            if (e + 3 < n) {
                float4 w = *(const float4*)(sr + e);
                float wa[4] = {w.x, w.y, w.z, w.w};
#pragma unroll
                for (int q = 0; q < 4; ++q)
                    if (wa[q] >= t0) { int p = atomicAdd(&ncand_s, 1); if (p < CAP) { cidx[p] = e + q; csim[p] = wa[q]; } }
            } else {
                for (int q = e; q < n; ++q) {
                    float v0 = sr[q];
                    if (v0 >= t0) { int p = atomicAdd(&ncand_s, 1); if (p < CAP) { cidx[p] = q; csim[p] = v0; } }
                }
            }
        }
    }
    __syncthreads();
    int m = min(ncand_s, CAP);

    // ---- health certificate: #{>= t0+EPS2} >= KSEL proves superset ----
    {
        int c2 = 0;
        for (int c = tid; c < m; c += 256) c2 += (csim[c] >= t0 + EPS2) ? 1 : 0;
#pragma unroll
        for (int off = 32; off; off >>= 1) c2 += __shfl_down(c2, off);
        if (lane == 0) atomicAdd(&c2_s, c2);
    }
    __syncthreads();
    bool healthy = (ncand_s <= CAP) && (c2_s >= KSEL);
    float s31, Wl;
    if (healthy) {
        // lex rank over stored sims -> s31 (unique via index tie-break)
        for (int c = tid; c < m; c += 256) {
            float mys = csim[c]; int myi = cidx[c]; int r = 0;
            for (int j = 0; j < m; ++j) {
                float vj = csim[j];
                r += (vj > mys || (vj == mys && cidx[j] < myi)) ? 1 : 0;
            }
            if (r == KSEL - 1) s31_s = mys;
        }
        __syncthreads();
        s31 = s31_s; Wl = EPS2;
    } else {
        // ---- fallback (expected ~0 rows): streaming bisection rebuild ----
        if (tid == 0) ncand_s = 0;
        __syncthreads();
        float lo = 0.0f, hi = 0.75f, thr = 0.0f;
        bool found = false;
        for (int it = 0; it < 30 && !found; ++it) {
            float mid = 0.5f * (lo + hi);
            int c = 0;
            for (int e = tid; e < n; e += 256) {
                float vv = BFS ? bf2f(((const unsigned short*)simrow)[e])
                               : (float)((const float*)simrow)[e];
                c += (vv >= mid) ? 1 : 0;
            }
#pragma unroll
            for (int off = 32; off; off >>= 1) c += __shfl_down(c, off);
            if (lane == 0) redi[wid] = c;
            __syncthreads();
            int tot = redi[0] + redi[1] + redi[2] + redi[3];
            __syncthreads();
            if (tot >= 40 && tot <= 600) { thr = mid; found = true; }
            else if (tot >= 40) lo = mid;
            else hi = mid;
        }
        if (!found) thr = lo;
        for (int e = tid; e < n; e += 256) {
            float vv = BFS ? bf2f(((const unsigned short*)simrow)[e])
                           : (float)((const float*)simrow)[e];
            if (vv >= thr) { int p = atomicAdd(&ncand_s, 1); if (p < CAP) { cidx[p] = e; csim[p] = vv; } }
        }
        __syncthreads();
        m = min(ncand_s, CAP);
        s31 = 0.0f; Wl = 1e30f;   // everything borderline -> full fp64 rank
    }

    // ---- classify: definite-in / borderline ----
    for (int c = tid; c < m; c += 256) {
        float sc = csim[c];
        if (sc > s31 + Wl) atomicAdd(&nhi_s, 1);
        else if (sc >= s31 - Wl) { int p = atomicAdd(&nbl_s, 1); if (p < CAP) blist[p] = c; }
    }
    __syncthreads();
    int nhi = nhi_s, nbl = min(nbl_s, CAP);
    int kneed = KSEL - nhi;   // >= 1 (def-in all have lex-rank < KSEL-1)

    // ---- fp64 recompute of borderline only (2-way ILP) ----
    double hr[4]; float w0e[4], w1e[4];
#pragma unroll
    for (int r = 0; r < 4; ++r) {
        int e = lane + 64 * r;
        w0e[r] = W0[e]; w1e[r] = W1[e];
        hr[r] = h64_of(F[(size_t)row * ISZ + e], w0e[r], w1e[r]);
    }
    double srow = snorm[row];
    for (int c = wid * 2; c < nbl; c += 8) {
        int s1 = blist[c];
        bool ok2 = (c + 1 < nbl);
        int s2 = ok2 ? blist[c + 1] : s1;
        int j1 = cidx[s1], j2 = cidx[s2];
        double a1 = 0.0, a2 = 0.0;
#pragma unroll
        for (int r = 0; r < 4; ++r) {
            int e = lane + 64 * r;
            a1 += hr[r] * h64_of(F[(size_t)j1 * ISZ + e], w0e[r], w1e[r]);
            a2 += hr[r] * h64_of(F[(size_t)j2 * ISZ + e], w0e[r], w1e[r]);
        }
#pragma unroll
        for (int off = 32; off; off >>= 1) {
            a1 += __shfl_down(a1, off);
            a2 += __shfl_down(a2, off);
        }
        if (lane == 0) {
            cval[s1] = a1 / (srow * snorm[j1]);
            if (ok2) cval[s2] = a2 / (srow * snorm[j2]);
        }
    }
    __syncthreads();

    // ---- zero row, then patch ----
    float* outp = OUT + (size_t)row * n;
    float4 z4 = make_float4(0.f, 0.f, 0.f, 0.f);
    for (int e = 4 * tid; e < n; e += 1024)
        if (e + 3 < n) *(float4*)(outp + e) = z4;
    for (int e = (n & ~3) + tid; e < n; e += 256) outp[e] = 0.0f;
    __syncthreads();
    for (int c = tid; c < m; c += 256)
        if (csim[c] > s31 + Wl) outp[cidx[c]] = fmaxf(csim[c], 0.0f);
    for (int b = tid; b < nbl; b += 256) {
        int slot = blist[b];
        double vv = cval[slot]; int myi = cidx[slot]; int r2 = 0;
        for (int j = 0; j < nbl; ++j) {
            int sj = blist[j]; double vj = cval[sj];
            r2 += (vj > vv || (vj == vv && cidx[sj] < myi)) ? 1 : 0;
        }
        if (r2 < kneed) outp[myi] = (float)fmax(vv, 0.0);
    }
}

extern "C" void kernel_launch(void* const* d_in, const int* in_sizes, int n_in,
                              void* d_out, int out_size, void* d_ws, size_t ws_size,
                              hipStream_t stream) {
    const float* F  = (const float*)d_in[0];
    const float* w0 = (const float*)d_in[1];
    const float* w1 = (const float*)d_in[2];
    float* out = (float*)d_out;
    int isz = in_sizes[1];           // 256
    int n = in_sizes[0] / isz;       // 10000

    char* ws = (char*)d_ws;
    size_t o_snorm = 0;
    size_t o_ebf   = o_snorm + (size_t)n * 8;
    size_t o_ebs   = o_ebf + (size_t)n * ISZ * 2;
    size_t o_t0    = o_ebs + (size_t)ISZ * NSAMP * 2;
    size_t o_sim   = (o_t0 + (size_t)n * 4 + 255) & ~(size_t)255;
    size_t need_bf = o_sim + (size_t)n * n * 2;

    double* snorm = (double*)(ws + o_snorm);
    __hip_bfloat16* Ebf = (__hip_bfloat16*)(ws + o_ebf);
    __hip_bfloat16* EbS = (__hip_bfloat16*)(ws + o_ebs);
    float* t0arr = (float*)(ws + o_t0);

    emb_kernel<<<n, 256, 0, stream>>>(F, w0, w1, Ebf, snorm, n);
    pack_samples<<<NSAMP, 256, 0, stream>>>(Ebf, EbS, n);
    prepass_t0<<<n, 128, 0, stream>>>(Ebf, EbS, t0arr, n);
    int nt = (n + 127) / 128;
    if (ws_size >= need_bf) {
        __hip_bfloat16* S = (__hip_bfloat16*)(ws + o_sim);
        gemm_st<__hip_bfloat16><<<dim3(nt, nt), 256, 0, stream>>>(Ebf, S, n);
        topk_sel<__hip_bfloat16><<<n, 256, 0, stream>>>(S, out, F, w0, w1, snorm, t0arr, n);
    } else {
        gemm_st<float><<<dim3(nt, nt), 256, 0, stream>>>(Ebf, out, n);
        topk_sel<float><<<n, 256, 0, stream>>>(out, out, F, w0, w1, snorm, t0arr, n);
    }
}

// Round 13
// 815.684 us; speedup vs baseline: 1.2045x; 1.0759x over previous
//
#include <hip/hip_runtime.h>
#include <hip/hip_bf16.h>
#include <math.h>

#define ISZ 256
#define KSEL 31      // keep top-(K+1) = 31
#define CMIN 64      // bisection window lower bound (margin over KSEL for bf16-GEMM error)
#define CEXIT 192    // bisection early-exit upper bound
#define NCAND 256    // candidate buffer cap (>= CEXIT + fp32-tie headroom)
#define NTH 512      // topk threads per block
#define NV4 5        // float4 slots per thread: 5*4*512 = 10240 >= 10000

typedef __attribute__((ext_vector_type(8))) short bf16x8;
typedef __attribute__((ext_vector_type(4))) float f32x4;

__device__ __forceinline__ double h64_of(float f, float w0, float w1) {
    return fmax((double)f * (double)w0, 0.0) * (double)w1;
}

// Eb = bf16 normalized embedding (MFMA operand); snorm = fp64 ||h||.
// (round-8 proven, verbatim)
__global__ __launch_bounds__(256) void emb_kernel(const float* __restrict__ F,
                                                  const float* __restrict__ w0,
                                                  const float* __restrict__ w1,
                                                  __hip_bfloat16* __restrict__ Eb,
                                                  double* __restrict__ snorm,
                                                  int n) {
    int row = blockIdx.x;
    int t = threadIdx.x;
    float f = F[(size_t)row * ISZ + t];
    double h64 = h64_of(f, w0[t], w1[t]);
    double ss = h64 * h64;
#pragma unroll
    for (int off = 32; off; off >>= 1) ss += __shfl_down(ss, off);
    __shared__ double red[4];
    if ((t & 63) == 0) red[t >> 6] = ss;
    __syncthreads();
    double tot = red[0] + red[1] + red[2] + red[3];
    double s = fmax(sqrt(tot), 1e-12);
    if (t == 0) snorm[row] = s;
    Eb[(size_t)row * ISZ + t] = __float2bfloat16((float)(h64 / s));
}

// S = Eb * Eb^T via MFMA 16x16x32 bf16, fp32 output into d_out.
// (round-8 proven, verbatim)
__global__ __launch_bounds__(256) void gemm_mfma(const __hip_bfloat16* __restrict__ Eb,
                                                 float* __restrict__ S, int n) {
    int bx = blockIdx.x, by = blockIdx.y;
    int row0 = by * 128, col0 = bx * 128;
    int tid = threadIdx.x, lane = tid & 63, wid = tid >> 6;
    int wr = wid >> 1, wc = wid & 1;
    int rbase = row0 + wr * 64 + (lane & 15);
    int cbase = col0 + wc * 64 + (lane & 15);
    int kg2 = ((lane >> 4) * 8) * 2;        // k-subgroup byte offset
    const char* Ep = (const char*)Eb;
    unsigned aoff[4], boff[4];
#pragma unroll
    for (int i = 0; i < 4; ++i) {
        aoff[i] = (unsigned)min(rbase + i * 16, n - 1) * (ISZ * 2) + kg2;
        boff[i] = (unsigned)min(cbase + i * 16, n - 1) * (ISZ * 2) + kg2;
    }
    f32x4 acc[4][4] = {};
#pragma unroll
    for (int kt = 0; kt < ISZ; kt += 32) {
        bf16x8 a[4], b[4];
#pragma unroll
        for (int i = 0; i < 4; ++i) a[i] = *(const bf16x8*)(Ep + aoff[i] + kt * 2);
#pragma unroll
        for (int j = 0; j < 4; ++j) b[j] = *(const bf16x8*)(Ep + boff[j] + kt * 2);
#pragma unroll
        for (int i = 0; i < 4; ++i)
#pragma unroll
            for (int j = 0; j < 4; ++j)
                acc[i][j] = __builtin_amdgcn_mfma_f32_16x16x32_bf16(a[i], b[j], acc[i][j], 0, 0, 0);
    }
    // C/D layout: col = lane&15, row = (lane>>4)*4 + r  [m89-verified]
    int orow = row0 + wr * 64 + (lane >> 4) * 4;
    int ocol = col0 + wc * 64 + (lane & 15);
#pragma unroll
    for (int i = 0; i < 4; ++i)
#pragma unroll
        for (int r = 0; r < 4; ++r) {
            int rr = orow + i * 16 + r;
            if (rr < n) {
#pragma unroll
                for (int j = 0; j < 4; ++j) {
                    int cc = ocol + j * 16;
                    if (cc < n) S[(size_t)rr * n + cc] = acc[i][j][r];
                }
            }
        }
}

// Round-8 proven per-row topk, re-parameterized to 512 threads/block:
// register-resident fp32 row, value-space bisection to candidate superset
// (count in [CMIN, CEXIT]; fp32 counts step by ~1 so the window is always
// found), fp64 recompute from raw inputs (2-way ILP x 8 waves) for exact
// top-KSEL with stable lowest-index ties, flags bitmask, masked relu rewrite
// from registers, fp64 value patch.
__global__ __launch_bounds__(NTH) void topk_mask(float* __restrict__ C,
                                                 const float* __restrict__ F,
                                                 const float* __restrict__ W0,
                                                 const float* __restrict__ W1,
                                                 const double* __restrict__ snorm,
                                                 int n) {
    __shared__ unsigned flags[320];   // 10000-bit keep mask
    __shared__ int redi[8];
    __shared__ int cand_idx[NCAND];
    __shared__ double cand_val[NCAND];
    __shared__ int ncand;
    int row = blockIdx.x;
    int tid = threadIdx.x;
    int lane = tid & 63, wid = tid >> 6;   // wid in 0..7
    float* rowp = C + (size_t)row * n;

    // ---- load row into registers (coalesced float4) ----
    float v[4 * NV4];
#pragma unroll
    for (int s = 0; s < NV4; ++s) {
        int e = 4 * tid + (4 * NTH) * s;
        if (e < n) {   // n%4==0, e%4==0 -> e+3 < n
            float4 w = *(const float4*)(rowp + e);
            v[s * 4 + 0] = w.x; v[s * 4 + 1] = w.y;
            v[s * 4 + 2] = w.z; v[s * 4 + 3] = w.w;
        } else {
#pragma unroll
            for (int q = 0; q < 4; ++q) v[s * 4 + q] = -1e30f;
        }
    }
    for (int q = tid; q < 320; q += NTH) flags[q] = 0;
    if (tid == 0) ncand = 0;
    __syncthreads();

    auto blockcount = [&](float t) -> int {
        int c = 0;
#pragma unroll
        for (int q = 0; q < 4 * NV4; ++q) c += (v[q] >= t) ? 1 : 0;
#pragma unroll
        for (int off = 32; off; off >>= 1) c += __shfl_down(c, off);
        if (lane == 0) redi[wid] = c;
        __syncthreads();
        int tot = 0;
#pragma unroll
        for (int w = 0; w < 8; ++w) tot += redi[w];
        __syncthreads();
        return tot;
    };

    // Invariant: count(>=lo) >= CMIN, count(>=hi) < CMIN.
    // count(>=0.75) == 1 (diag only) < CMIN; count(>=0) ~ n/2 > CEXIT.
    float lo = 0.0f, hi = 0.75f, thr = 0.0f;
    bool found = false;
    for (int it = 0; it < 30 && !found; ++it) {
        float mid = 0.5f * (lo + hi);
        int c = blockcount(mid);
        if (c >= CMIN && c <= CEXIT) { thr = mid; found = true; }
        else if (c >= CMIN) lo = mid;
        else hi = mid;
    }
    if (!found) thr = lo;   // fp32 values: window miss needs 129+ one-ulp ties

    // ---- collect candidate indices ----
#pragma unroll
    for (int s = 0; s < NV4; ++s) {
        int e = 4 * tid + (4 * NTH) * s;
#pragma unroll
        for (int j = 0; j < 4; ++j) {
            if (v[s * 4 + j] >= thr) {
                int pos = atomicAdd(&ncand, 1);
                if (pos < NCAND) cand_idx[pos] = e + j;
            }
        }
    }
    __syncthreads();
    int m = min(ncand, NCAND);

    // ---- fp64 recompute from raw inputs, 2 candidates/iter x 8 waves ----
    double hr[4];
    float w0e[4], w1e[4];
#pragma unroll
    for (int r = 0; r < 4; ++r) {
        int e = lane + 64 * r;
        w0e[r] = W0[e];
        w1e[r] = W1[e];
        hr[r] = h64_of(F[(size_t)row * ISZ + e], w0e[r], w1e[r]);
    }
    double srow = snorm[row];
    for (int c = wid * 2; c < m; c += 16) {
        int j1 = cand_idx[c];
        int c2ok = (c + 1 < m);
        int j2 = c2ok ? cand_idx[c + 1] : j1;
        double a1 = 0.0, a2 = 0.0;
#pragma unroll
        for (int r = 0; r < 4; ++r) {
            int e = lane + 64 * r;
            float f1 = F[(size_t)j1 * ISZ + e];
            float f2 = F[(size_t)j2 * ISZ + e];
            a1 += hr[r] * h64_of(f1, w0e[r], w1e[r]);
            a2 += hr[r] * h64_of(f2, w0e[r], w1e[r]);
        }
#pragma unroll
        for (int off = 32; off; off >>= 1) {
            a1 += __shfl_down(a1, off);
            a2 += __shfl_down(a2, off);
        }
        if (lane == 0) {
            cand_val[c] = a1 / (srow * snorm[j1]);
            if (c2ok) cand_val[c + 1] = a2 / (srow * snorm[j2]);
        }
    }
    __syncthreads();

    // ---- exact top-KSEL among candidates, stable lowest-index ties ----
    int myrank = KSEL;
    if (tid < m) {
        double vv = cand_val[tid];
        int idx = cand_idx[tid];
        int rank = 0;
        for (int j2 = 0; j2 < m; ++j2) {
            double vj = cand_val[j2];
            rank += (vj > vv || (vj == vv && cand_idx[j2] < idx)) ? 1 : 0;
        }
        myrank = rank;
        if (rank < KSEL) atomicOr(&flags[idx >> 5], 1u << (idx & 31));
    }
    __syncthreads();

    // ---- masked relu rewrite from registers ----
#pragma unroll
    for (int s = 0; s < NV4; ++s) {
        int e = 4 * tid + (4 * NTH) * s;
        if (e >= n) continue;
        float vals[4] = {v[s * 4 + 0], v[s * 4 + 1], v[s * 4 + 2], v[s * 4 + 3]};
        float o[4];
#pragma unroll
        for (int j = 0; j < 4; ++j) {
            int q = e + j;
            bool keep = (flags[q >> 5] >> (q & 31)) & 1u;
            o[j] = (keep && vals[j] > 0.0f) ? vals[j] : 0.0f;
        }
        *(float4*)(rowp + e) = make_float4(o[0], o[1], o[2], o[3]);
    }
    __syncthreads();   // order bulk writes before the patch

    // ---- fp64 value patch of kept entries ----
    if (tid < m && myrank < KSEL) {
        rowp[cand_idx[tid]] = (float)fmax(cand_val[tid], 0.0);
    }
}

extern "C" void kernel_launch(void* const* d_in, const int* in_sizes, int n_in,
                              void* d_out, int out_size, void* d_ws, size_t ws_size,
                              hipStream_t stream) {
    const float* F  = (const float*)d_in[0];
    const float* w0 = (const float*)d_in[1];
    const float* w1 = (const float*)d_in[2];
    float* out = (float*)d_out;
    int isz = in_sizes[1];           // 256
    int n = in_sizes[0] / isz;       // 10000

    char* ws = (char*)d_ws;
    __hip_bfloat16* Ebf = (__hip_bfloat16*)ws;              // 5.12 MB
    double* snorm = (double*)(ws + (size_t)n * ISZ * 2);    // 80 KB

    emb_kernel<<<n, 256, 0, stream>>>(F, w0, w1, Ebf, snorm, n);
    int nt = (n + 127) / 128;
    gemm_mfma<<<dim3(nt, nt), 256, 0, stream>>>(Ebf, out, n);
    topk_mask<<<n, NTH, 0, stream>>>(out, F, w0, w1, snorm, n);
}

// Round 14
// 809.691 us; speedup vs baseline: 1.2134x; 1.0074x over previous
//
#include <hip/hip_runtime.h>
#include <hip/hip_bf16.h>
#include <math.h>

#define ISZ 256
#define KSEL 31      // keep top-(K+1) = 31
#define CMIN 64      // candidate-count target (margin over KSEL for bf16-GEMM error)
#define NCAND 256    // candidate buffer cap (m <= ~116 by histogram construction)
#define NBINS 512    // coarse histogram bins
#define BLO 0.0f
#define BHI 0.80f    // sims are cos of nonneg vectors: in [0,1], off-diag < ~0.7

typedef __attribute__((ext_vector_type(8))) short bf16x8;
typedef __attribute__((ext_vector_type(4))) float f32x4;

__device__ __forceinline__ double h64_of(float f, float w0, float w1) {
    return fmax((double)f * (double)w0, 0.0) * (double)w1;
}

// Eb = bf16 normalized embedding (MFMA operand); snorm = fp64 ||h||.
// (round-8 proven, verbatim)
__global__ __launch_bounds__(256) void emb_kernel(const float* __restrict__ F,
                                                  const float* __restrict__ w0,
                                                  const float* __restrict__ w1,
                                                  __hip_bfloat16* __restrict__ Eb,
                                                  double* __restrict__ snorm,
                                                  int n) {
    int row = blockIdx.x;
    int t = threadIdx.x;
    float f = F[(size_t)row * ISZ + t];
    double h64 = h64_of(f, w0[t], w1[t]);
    double ss = h64 * h64;
#pragma unroll
    for (int off = 32; off; off >>= 1) ss += __shfl_down(ss, off);
    __shared__ double red[4];
    if ((t & 63) == 0) red[t >> 6] = ss;
    __syncthreads();
    double tot = red[0] + red[1] + red[2] + red[3];
    double s = fmax(sqrt(tot), 1e-12);
    if (t == 0) snorm[row] = s;
    Eb[(size_t)row * ISZ + t] = __float2bfloat16((float)(h64 / s));
}

// S = Eb * Eb^T via MFMA 16x16x32 bf16, fp32 output into d_out.
// (round-8 proven, verbatim)
__global__ __launch_bounds__(256) void gemm_mfma(const __hip_bfloat16* __restrict__ Eb,
                                                 float* __restrict__ S, int n) {
    int bx = blockIdx.x, by = blockIdx.y;
    int row0 = by * 128, col0 = bx * 128;
    int tid = threadIdx.x, lane = tid & 63, wid = tid >> 6;
    int wr = wid >> 1, wc = wid & 1;
    int rbase = row0 + wr * 64 + (lane & 15);
    int cbase = col0 + wc * 64 + (lane & 15);
    int kg2 = ((lane >> 4) * 8) * 2;        // k-subgroup byte offset
    const char* Ep = (const char*)Eb;
    unsigned aoff[4], boff[4];
#pragma unroll
    for (int i = 0; i < 4; ++i) {
        aoff[i] = (unsigned)min(rbase + i * 16, n - 1) * (ISZ * 2) + kg2;
        boff[i] = (unsigned)min(cbase + i * 16, n - 1) * (ISZ * 2) + kg2;
    }
    f32x4 acc[4][4] = {};
#pragma unroll
    for (int kt = 0; kt < ISZ; kt += 32) {
        bf16x8 a[4], b[4];
#pragma unroll
        for (int i = 0; i < 4; ++i) a[i] = *(const bf16x8*)(Ep + aoff[i] + kt * 2);
#pragma unroll
        for (int j = 0; j < 4; ++j) b[j] = *(const bf16x8*)(Ep + boff[j] + kt * 2);
#pragma unroll
        for (int i = 0; i < 4; ++i)
#pragma unroll
            for (int j = 0; j < 4; ++j)
                acc[i][j] = __builtin_amdgcn_mfma_f32_16x16x32_bf16(a[i], b[j], acc[i][j], 0, 0, 0);
    }
    // C/D layout: col = lane&15, row = (lane>>4)*4 + r  [m89-verified]
    int orow = row0 + wr * 64 + (lane >> 4) * 4;
    int ocol = col0 + wc * 64 + (lane & 15);
#pragma unroll
    for (int i = 0; i < 4; ++i)
#pragma unroll
        for (int r = 0; r < 4; ++r) {
            int rr = orow + i * 16 + r;
            if (rr < n) {
#pragma unroll
                for (int j = 0; j < 4; ++j) {
                    int cc = ocol + j * 16;
                    if (cc < n) S[(size_t)rr * n + cc] = acc[i][j][r];
                }
            }
        }
}

// Round-8 topk structure at 256 threads; bisection replaced by a 2-level LDS
// histogram (2 data passes, ~8 barriers vs 10-24 passes / 20-48 barriers);
// fp64 recompute 4-way ILP. Collection/rank/rewrite/patch logic identical.
__global__ __launch_bounds__(256) void topk_mask(float* __restrict__ C,
                                                 const float* __restrict__ F,
                                                 const float* __restrict__ W0,
                                                 const float* __restrict__ W1,
                                                 const double* __restrict__ snorm,
                                                 int n) {
    __shared__ unsigned flags[320];   // 10000-bit keep mask
    __shared__ int hist[NBINS];       // coarse; first 256 reused for refine
    __shared__ int cand_idx[NCAND];
    __shared__ double cand_val[NCAND];
    __shared__ int ncand;
    __shared__ float rlo_s, rhi_s, thr_s;
    __shared__ int need_s;
    int row = blockIdx.x;
    int tid = threadIdx.x;
    int lane = tid & 63, wid = tid >> 6;   // wid 0..3
    float* rowp = C + (size_t)row * n;

    // ---- load row into registers (coalesced float4) ----
    float v[40];
#pragma unroll
    for (int s = 0; s < 10; ++s) {
        int e = 4 * tid + 1024 * s;
        if (e < n) {
            float4 w = *(const float4*)(rowp + e);
            v[s * 4 + 0] = w.x; v[s * 4 + 1] = w.y;
            v[s * 4 + 2] = w.z; v[s * 4 + 3] = w.w;
        } else {
#pragma unroll
            for (int q = 0; q < 4; ++q) v[s * 4 + q] = -1e30f;
        }
    }
    for (int q = tid; q < 320; q += 256) flags[q] = 0;
    for (int q = tid; q < NBINS; q += 256) hist[q] = 0;
    if (tid == 0) ncand = 0;
    __syncthreads();

    // ---- coarse histogram over [BLO, BHI), clamped ----
    const float BSCALE = (float)NBINS / (BHI - BLO);
#pragma unroll
    for (int q = 0; q < 40; ++q) {
        int b = (int)((v[q] - BLO) * BSCALE);
        b = max(0, min(NBINS - 1, b));
        atomicAdd(&hist[b], 1);
    }
    __syncthreads();
    // top-down scan: first bin where cumulative count >= CMIN
    if (tid == 0) {
        int cum = 0, b = NBINS - 1;
        for (; b > 0; --b) { cum += hist[b]; if (cum >= CMIN) break; }
        if (cum < CMIN) cum += hist[0];          // b == 0 catch-all
        rlo_s = BLO + (float)b * (1.0f / BSCALE);
        rhi_s = BLO + (float)(b + 1) * (1.0f / BSCALE);
        need_s = CMIN - (cum - hist[b]);         // >= 1 needed from bin b
    }
    __syncthreads();
    float rlo = rlo_s, rhi = rhi_s;
    int need = need_s;
    // ---- refine histogram (256 sub-bins within boundary bin) ----
    for (int q = tid; q < 256; q += 256) hist[q] = 0;
    __syncthreads();
    const float RSCALE = 256.0f / (rhi - rlo);
#pragma unroll
    for (int q = 0; q < 40; ++q) {
        float x = v[q];
        if (x >= rlo && x < rhi) {
            int b = (int)((x - rlo) * RSCALE);
            b = max(0, min(255, b));
            atomicAdd(&hist[b], 1);
        }
    }
    __syncthreads();
    if (tid == 0) {
        int cum = 0, b = 255;
        for (; b > 0; --b) { cum += hist[b]; if (cum >= need) break; }
        thr_s = rlo + (float)b * (1.0f / RSCALE);   // b==0 -> thr = rlo (safe)
    }
    __syncthreads();
    float thr = thr_s;
    // count{v >= thr} in [CMIN-slop, CMIN-1 + subbin-ties + slop] ~ [61, ~116]

    // ---- collect candidate indices ----
#pragma unroll
    for (int s = 0; s < 10; ++s) {
        int e = 4 * tid + 1024 * s;
#pragma unroll
        for (int j = 0; j < 4; ++j) {
            if (v[s * 4 + j] >= thr) {
                int pos = atomicAdd(&ncand, 1);
                if (pos < NCAND) cand_idx[pos] = e + j;
            }
        }
    }
    __syncthreads();
    int m = min(ncand, NCAND);

    // ---- fp64 recompute from raw inputs, 4 candidates/iter x 4 waves ----
    double hr[4];
    float w0e[4], w1e[4];
#pragma unroll
    for (int r = 0; r < 4; ++r) {
        int e = lane + 64 * r;
        w0e[r] = W0[e];
        w1e[r] = W1[e];
        hr[r] = h64_of(F[(size_t)row * ISZ + e], w0e[r], w1e[r]);
    }
    double srow = snorm[row];
    for (int c = wid * 4; c < m; c += 16) {
        int j0 = cand_idx[c];
        int j1 = cand_idx[min(c + 1, m - 1)];
        int j2 = cand_idx[min(c + 2, m - 1)];
        int j3 = cand_idx[min(c + 3, m - 1)];
        double a0 = 0.0, a1 = 0.0, a2 = 0.0, a3 = 0.0;
#pragma unroll
        for (int r = 0; r < 4; ++r) {
            int e = lane + 64 * r;
            float f0 = F[(size_t)j0 * ISZ + e];
            float f1 = F[(size_t)j1 * ISZ + e];
            float f2 = F[(size_t)j2 * ISZ + e];
            float f3 = F[(size_t)j3 * ISZ + e];
            a0 += hr[r] * h64_of(f0, w0e[r], w1e[r]);
            a1 += hr[r] * h64_of(f1, w0e[r], w1e[r]);
            a2 += hr[r] * h64_of(f2, w0e[r], w1e[r]);
            a3 += hr[r] * h64_of(f3, w0e[r], w1e[r]);
        }
#pragma unroll
        for (int off = 32; off; off >>= 1) {
            a0 += __shfl_down(a0, off);
            a1 += __shfl_down(a1, off);
            a2 += __shfl_down(a2, off);
            a3 += __shfl_down(a3, off);
        }
        if (lane == 0) {
            cand_val[c] = a0 / (srow * snorm[j0]);
            if (c + 1 < m) cand_val[c + 1] = a1 / (srow * snorm[j1]);
            if (c + 2 < m) cand_val[c + 2] = a2 / (srow * snorm[j2]);
            if (c + 3 < m) cand_val[c + 3] = a3 / (srow * snorm[j3]);
        }
    }
    __syncthreads();

    // ---- exact top-KSEL among candidates, stable lowest-index ties ----
    int myrank = KSEL;
    if (tid < m) {
        double vv = cand_val[tid];
        int idx = cand_idx[tid];
        int rank = 0;
        for (int j2 = 0; j2 < m; ++j2) {
            double vj = cand_val[j2];
            rank += (vj > vv || (vj == vv && cand_idx[j2] < idx)) ? 1 : 0;
        }
        myrank = rank;
        if (rank < KSEL) atomicOr(&flags[idx >> 5], 1u << (idx & 31));
    }
    __syncthreads();

    // ---- masked relu rewrite from registers ----
#pragma unroll
    for (int s = 0; s < 10; ++s) {
        int e = 4 * tid + 1024 * s;
        if (e >= n) continue;
        float vals[4] = {v[s * 4 + 0], v[s * 4 + 1], v[s * 4 + 2], v[s * 4 + 3]};
        float o[4];
#pragma unroll
        for (int j = 0; j < 4; ++j) {
            int q = e + j;
            bool keep = (flags[q >> 5] >> (q & 31)) & 1u;
            o[j] = (keep && vals[j] > 0.0f) ? vals[j] : 0.0f;
        }
        *(float4*)(rowp + e) = make_float4(o[0], o[1], o[2], o[3]);
    }
    __syncthreads();   // order bulk writes before the patch

    // ---- fp64 value patch of kept entries ----
    if (tid < m && myrank < KSEL) {
        rowp[cand_idx[tid]] = (float)fmax(cand_val[tid], 0.0);
    }
}

extern "C" void kernel_launch(void* const* d_in, const int* in_sizes, int n_in,
                              void* d_out, int out_size, void* d_ws, size_t ws_size,
                              hipStream_t stream) {
    const float* F  = (const float*)d_in[0];
    const float* w0 = (const float*)d_in[1];
    const float* w1 = (const float*)d_in[2];
    float* out = (float*)d_out;
    int isz = in_sizes[1];           // 256
    int n = in_sizes[0] / isz;       // 10000

    char* ws = (char*)d_ws;
    __hip_bfloat16* Ebf = (__hip_bfloat16*)ws;              // 5.12 MB
    double* snorm = (double*)(ws + (size_t)n * ISZ * 2);    // 80 KB

    emb_kernel<<<n, 256, 0, stream>>>(F, w0, w1, Ebf, snorm, n);
    int nt = (n + 127) / 128;
    gemm_mfma<<<dim3(nt, nt), 256, 0, stream>>>(Ebf, out, n);
    topk_mask<<<n, 256, 0, stream>>>(out, F, w0, w1, snorm, n);
}

// Round 15
// 608.110 us; speedup vs baseline: 1.6157x; 1.3315x over previous
//
#include <hip/hip_runtime.h>
#include <hip/hip_bf16.h>
#include <math.h>

#define ISZ 256
#define KSEL 31      // keep top-(K+1) = 31
#define CMIN 64      // min candidate count (margin over KSEL for bf16-GEMM error)
#define CEXIT 192    // bisection-fallback early-exit upper bound
#define NCAND 320    // candidate buffer cap
#define ZSTAT 2.25f  // stats threshold: thr = mean + ZSTAT*sd (~120 cands)

typedef __attribute__((ext_vector_type(8))) short bf16x8;
typedef __attribute__((ext_vector_type(4))) float f32x4;

__device__ __forceinline__ double h64_of(float f, float w0, float w1) {
    return fmax((double)f * (double)w0, 0.0) * (double)w1;
}

// Eb = bf16 normalized embedding (MFMA operand); snorm = fp64 ||h||.
// (round-8 proven, verbatim)
__global__ __launch_bounds__(256) void emb_kernel(const float* __restrict__ F,
                                                  const float* __restrict__ w0,
                                                  const float* __restrict__ w1,
                                                  __hip_bfloat16* __restrict__ Eb,
                                                  double* __restrict__ snorm,
                                                  int n) {
    int row = blockIdx.x;
    int t = threadIdx.x;
    float f = F[(size_t)row * ISZ + t];
    double h64 = h64_of(f, w0[t], w1[t]);
    double ss = h64 * h64;
#pragma unroll
    for (int off = 32; off; off >>= 1) ss += __shfl_down(ss, off);
    __shared__ double red[4];
    if ((t & 63) == 0) red[t >> 6] = ss;
    __syncthreads();
    double tot = red[0] + red[1] + red[2] + red[3];
    double s = fmax(sqrt(tot), 1e-12);
    if (t == 0) snorm[row] = s;
    Eb[(size_t)row * ISZ + t] = __float2bfloat16((float)(h64 / s));
}

// S = Eb * Eb^T via MFMA 16x16x32 bf16, fp32 output. (round-8 proven, verbatim)
__global__ __launch_bounds__(256) void gemm_mfma(const __hip_bfloat16* __restrict__ Eb,
                                                 float* __restrict__ S, int n) {
    int bx = blockIdx.x, by = blockIdx.y;
    int row0 = by * 128, col0 = bx * 128;
    int tid = threadIdx.x, lane = tid & 63, wid = tid >> 6;
    int wr = wid >> 1, wc = wid & 1;
    int rbase = row0 + wr * 64 + (lane & 15);
    int cbase = col0 + wc * 64 + (lane & 15);
    int kg2 = ((lane >> 4) * 8) * 2;        // k-subgroup byte offset
    const char* Ep = (const char*)Eb;
    unsigned aoff[4], boff[4];
#pragma unroll
    for (int i = 0; i < 4; ++i) {
        aoff[i] = (unsigned)min(rbase + i * 16, n - 1) * (ISZ * 2) + kg2;
        boff[i] = (unsigned)min(cbase + i * 16, n - 1) * (ISZ * 2) + kg2;
    }
    f32x4 acc[4][4] = {};
#pragma unroll
    for (int kt = 0; kt < ISZ; kt += 32) {
        bf16x8 a[4], b[4];
#pragma unroll
        for (int i = 0; i < 4; ++i) a[i] = *(const bf16x8*)(Ep + aoff[i] + kt * 2);
#pragma unroll
        for (int j = 0; j < 4; ++j) b[j] = *(const bf16x8*)(Ep + boff[j] + kt * 2);
#pragma unroll
        for (int i = 0; i < 4; ++i)
#pragma unroll
            for (int j = 0; j < 4; ++j)
                acc[i][j] = __builtin_amdgcn_mfma_f32_16x16x32_bf16(a[i], b[j], acc[i][j], 0, 0, 0);
    }
    // C/D layout: col = lane&15, row = (lane>>4)*4 + r  [m89-verified]
    int orow = row0 + wr * 64 + (lane >> 4) * 4;
    int ocol = col0 + wc * 64 + (lane & 15);
#pragma unroll
    for (int i = 0; i < 4; ++i)
#pragma unroll
        for (int r = 0; r < 4; ++r) {
            int rr = orow + i * 16 + r;
            if (rr < n) {
#pragma unroll
                for (int j = 0; j < 4; ++j) {
                    int cc = ocol + j * 16;
                    if (cc < n) S[(size_t)rr * n + cc] = acc[i][j][r];
                }
            }
        }
}

// Round-8 topk skeleton with: (1) stats threshold (mean+Z*sd over the
// register row) with verbatim-R8 bisection fallback when count outside
// [CMIN, NCAND]; (2) 4-way-ILP fp64 recompute; (3) PATCHONLY mode: d_out is
// pre-zeroed by memset, sims live in ws, only kept values are written.
template <bool PATCHONLY>
__global__ __launch_bounds__(256) void topk_mask(const float* SIM, float* OUT,
                                                 const float* __restrict__ F,
                                                 const float* __restrict__ W0,
                                                 const float* __restrict__ W1,
                                                 const double* __restrict__ snorm,
                                                 int n) {
    __shared__ unsigned flags[320];   // 10000-bit keep mask (legacy mode only)
    __shared__ float redf[8];
    __shared__ int redi[4];
    __shared__ int cand_idx[NCAND];
    __shared__ double cand_val[NCAND];
    __shared__ int rankarr[NCAND];
    __shared__ int ncand;
    __shared__ float thr_sh;
    int row = blockIdx.x;
    int tid = threadIdx.x;
    int lane = tid & 63, wid = tid >> 6;
    const float* simp = SIM + (size_t)row * n;
    float* outp = OUT + (size_t)row * n;

    // ---- load row into registers (coalesced float4) ----
    float v[40];
#pragma unroll
    for (int s = 0; s < 10; ++s) {
        int e = 4 * tid + 1024 * s;
        if (e < n) {
            float4 w = *(const float4*)(simp + e);
            v[s * 4 + 0] = w.x; v[s * 4 + 1] = w.y;
            v[s * 4 + 2] = w.z; v[s * 4 + 3] = w.w;
        } else {
#pragma unroll
            for (int q = 0; q < 4; ++q) v[s * 4 + q] = -1e30f;
        }
    }
    if constexpr (!PATCHONLY)
        for (int q = tid; q < 320; q += 256) flags[q] = 0;
    if (tid == 0) ncand = 0;
    __syncthreads();

    // ---- row stats (valid elements only) ----
    {
        float s1 = 0.0f, s2 = 0.0f;
#pragma unroll
        for (int s = 0; s < 10; ++s) {
            int e = 4 * tid + 1024 * s;
            if (e < n) {
#pragma unroll
                for (int j = 0; j < 4; ++j) {
                    float x = v[s * 4 + j];
                    s1 += x;
                    s2 += x * x;
                }
            }
        }
#pragma unroll
        for (int off = 32; off; off >>= 1) {
            s1 += __shfl_down(s1, off);
            s2 += __shfl_down(s2, off);
        }
        if (lane == 0) { redf[wid] = s1; redf[wid + 4] = s2; }
        __syncthreads();
        if (tid == 0) {
            float S1 = redf[0] + redf[1] + redf[2] + redf[3];
            float S2 = redf[4] + redf[5] + redf[6] + redf[7];
            float mean = S1 / (float)n;
            float var = fmaxf(S2 / (float)n - mean * mean, 1e-12f);
            thr_sh = mean + ZSTAT * sqrtf(var);
        }
        __syncthreads();
    }
    float thr = thr_sh;

    auto blockcount = [&](float t) -> int {
        int c = 0;
#pragma unroll
        for (int q = 0; q < 40; ++q) c += (v[q] >= t) ? 1 : 0;
#pragma unroll
        for (int off = 32; off; off >>= 1) c += __shfl_down(c, off);
        if (lane == 0) redi[wid] = c;
        __syncthreads();
        int tot = redi[0] + redi[1] + redi[2] + redi[3];
        __syncthreads();
        return tot;
    };

    auto collect = [&](float t) {
#pragma unroll
        for (int s = 0; s < 10; ++s) {
            int e = 4 * tid + 1024 * s;
#pragma unroll
            for (int j = 0; j < 4; ++j) {
                if (v[s * 4 + j] >= t) {
                    int pos = atomicAdd(&ncand, 1);
                    if (pos < NCAND) cand_idx[pos] = e + j;
                }
            }
        }
        __syncthreads();
    };

    collect(thr);
    if (ncand < CMIN || ncand > NCAND) {
        // ---- fallback: verbatim round-8 bisection ----
        __syncthreads();
        if (tid == 0) ncand = 0;
        __syncthreads();
        float lo = 0.0f, hi = 0.75f;
        thr = 0.0f;
        bool found = false;
        for (int it = 0; it < 30 && !found; ++it) {
            float mid = 0.5f * (lo + hi);
            int c = blockcount(mid);
            if (c >= CMIN && c <= CEXIT) { thr = mid; found = true; }
            else if (c >= CMIN) lo = mid;
            else hi = mid;
        }
        if (!found) thr = lo;
        collect(thr);
    }
    int m = min(ncand, NCAND);

    // ---- fp64 recompute from raw inputs, 4 candidates/iter x 4 waves ----
    double hr[4];
    float w0e[4], w1e[4];
#pragma unroll
    for (int r = 0; r < 4; ++r) {
        int e = lane + 64 * r;
        w0e[r] = W0[e];
        w1e[r] = W1[e];
        hr[r] = h64_of(F[(size_t)row * ISZ + e], w0e[r], w1e[r]);
    }
    double srow = snorm[row];
    for (int c = wid * 4; c < m; c += 16) {
        int j0 = cand_idx[c];
        int j1 = cand_idx[min(c + 1, m - 1)];
        int j2 = cand_idx[min(c + 2, m - 1)];
        int j3 = cand_idx[min(c + 3, m - 1)];
        double a0 = 0.0, a1 = 0.0, a2 = 0.0, a3 = 0.0;
#pragma unroll
        for (int r = 0; r < 4; ++r) {
            int e = lane + 64 * r;
            float f0 = F[(size_t)j0 * ISZ + e];
            float f1 = F[(size_t)j1 * ISZ + e];
            float f2 = F[(size_t)j2 * ISZ + e];
            float f3 = F[(size_t)j3 * ISZ + e];
            a0 += hr[r] * h64_of(f0, w0e[r], w1e[r]);
            a1 += hr[r] * h64_of(f1, w0e[r], w1e[r]);
            a2 += hr[r] * h64_of(f2, w0e[r], w1e[r]);
            a3 += hr[r] * h64_of(f3, w0e[r], w1e[r]);
        }
#pragma unroll
        for (int off = 32; off; off >>= 1) {
            a0 += __shfl_down(a0, off);
            a1 += __shfl_down(a1, off);
            a2 += __shfl_down(a2, off);
            a3 += __shfl_down(a3, off);
        }
        if (lane == 0) {
            cand_val[c] = a0 / (srow * snorm[j0]);
            if (c + 1 < m) cand_val[c + 1] = a1 / (srow * snorm[j1]);
            if (c + 2 < m) cand_val[c + 2] = a2 / (srow * snorm[j2]);
            if (c + 3 < m) cand_val[c + 3] = a3 / (srow * snorm[j3]);
        }
    }
    __syncthreads();

    // ---- exact top-KSEL rank (strided; stable lowest-index ties) ----
    for (int c = tid; c < m; c += 256) {
        double vv = cand_val[c];
        int idx = cand_idx[c];
        int rank = 0;
        for (int j2 = 0; j2 < m; ++j2) {
            double vj = cand_val[j2];
            rank += (vj > vv || (vj == vv && cand_idx[j2] < idx)) ? 1 : 0;
        }
        rankarr[c] = rank;
        if constexpr (!PATCHONLY) {
            if (rank < KSEL) atomicOr(&flags[idx >> 5], 1u << (idx & 31));
        }
    }
    __syncthreads();

    if constexpr (!PATCHONLY) {
        // ---- masked relu rewrite from registers ----
#pragma unroll
        for (int s = 0; s < 10; ++s) {
            int e = 4 * tid + 1024 * s;
            if (e >= n) continue;
            float vals[4] = {v[s * 4 + 0], v[s * 4 + 1], v[s * 4 + 2], v[s * 4 + 3]};
            float o[4];
#pragma unroll
            for (int j = 0; j < 4; ++j) {
                int q = e + j;
                bool keep = (flags[q >> 5] >> (q & 31)) & 1u;
                o[j] = (keep && vals[j] > 0.0f) ? vals[j] : 0.0f;
            }
            *(float4*)(outp + e) = make_float4(o[0], o[1], o[2], o[3]);
        }
        __syncthreads();   // order bulk writes before the patch
    }

    // ---- fp64 value patch of kept entries ----
    for (int c = tid; c < m; c += 256) {
        if (rankarr[c] < KSEL)
            outp[cand_idx[c]] = (float)fmax(cand_val[c], 0.0);
    }
}

extern "C" void kernel_launch(void* const* d_in, const int* in_sizes, int n_in,
                              void* d_out, int out_size, void* d_ws, size_t ws_size,
                              hipStream_t stream) {
    const float* F  = (const float*)d_in[0];
    const float* w0 = (const float*)d_in[1];
    const float* w1 = (const float*)d_in[2];
    float* out = (float*)d_out;
    int isz = in_sizes[1];           // 256
    int n = in_sizes[0] / isz;       // 10000

    char* ws = (char*)d_ws;
    __hip_bfloat16* Ebf = (__hip_bfloat16*)ws;                       // 5.12 MB
    double* snorm = (double*)(ws + (size_t)n * ISZ * 2);             // 80 KB
    size_t o_sim = (((size_t)n * ISZ * 2 + (size_t)n * 8) + 255) & ~(size_t)255;
    size_t need = o_sim + (size_t)n * n * 4;                         // +400 MB

    int nt = (n + 127) / 128;
    emb_kernel<<<n, 256, 0, stream>>>(F, w0, w1, Ebf, snorm, n);
    if (ws_size >= need) {
        float* S = (float*)(ws + o_sim);
        hipMemsetAsync(d_out, 0, (size_t)n * n * sizeof(float), stream);
        gemm_mfma<<<dim3(nt, nt), 256, 0, stream>>>(Ebf, S, n);
        topk_mask<true><<<n, 256, 0, stream>>>(S, out, F, w0, w1, snorm, n);
    } else {
        gemm_mfma<<<dim3(nt, nt), 256, 0, stream>>>(Ebf, out, n);
        topk_mask<false><<<n, 256, 0, stream>>>(out, out, F, w0, w1, snorm, n);
    }
}

// Round 16
// 551.349 us; speedup vs baseline: 1.7820x; 1.1029x over previous
//
#include <hip/hip_runtime.h>
#include <hip/hip_bf16.h>
#include <math.h>

#define ISZ 256
#define KSEL 31      // keep top-(K+1) = 31
#define CMIN 64      // min candidate count (margin over KSEL for bf16-GEMM error)
#define CEXIT 192    // bisection-fallback early-exit upper bound
#define NCAND 320    // candidate buffer cap
#define NSEL 64      // stored-rank prefilter size (superset of true top-31)
#define ZSTAT 2.25f  // stats threshold: thr = mean + ZSTAT*sd (~120 cands)

typedef __attribute__((ext_vector_type(8))) short bf16x8;
typedef __attribute__((ext_vector_type(4))) float f32x4;

__device__ __forceinline__ double h64_of(float f, float w0, float w1) {
    return fmax((double)f * (double)w0, 0.0) * (double)w1;
}

// Eb = bf16 normalized embedding (MFMA operand); snorm = fp64 ||h||.
// (round-8 proven, verbatim)
__global__ __launch_bounds__(256) void emb_kernel(const float* __restrict__ F,
                                                  const float* __restrict__ w0,
                                                  const float* __restrict__ w1,
                                                  __hip_bfloat16* __restrict__ Eb,
                                                  double* __restrict__ snorm,
                                                  int n) {
    int row = blockIdx.x;
    int t = threadIdx.x;
    float f = F[(size_t)row * ISZ + t];
    double h64 = h64_of(f, w0[t], w1[t]);
    double ss = h64 * h64;
#pragma unroll
    for (int off = 32; off; off >>= 1) ss += __shfl_down(ss, off);
    __shared__ double red[4];
    if ((t & 63) == 0) red[t >> 6] = ss;
    __syncthreads();
    double tot = red[0] + red[1] + red[2] + red[3];
    double s = fmax(sqrt(tot), 1e-12);
    if (t == 0) snorm[row] = s;
    Eb[(size_t)row * ISZ + t] = __float2bfloat16((float)(h64 / s));
}

// S = Eb * Eb^T via MFMA 16x16x32 bf16, fp32 output. Round-8 proven MFMA core
// + NEW: per-wave LDS-staged epilogue (wave-private 64x65 tile, no barriers)
// so each 16-lane quad stores 256 B contiguous (float4) instead of 64 B.
__global__ __launch_bounds__(256) void gemm_mfma(const __hip_bfloat16* __restrict__ Eb,
                                                 float* __restrict__ S, int n) {
    __shared__ float lds[4][64][65];
    int bx = blockIdx.x, by = blockIdx.y;
    int row0 = by * 128, col0 = bx * 128;
    int tid = threadIdx.x, lane = tid & 63, wid = tid >> 6;
    int wr = wid >> 1, wc = wid & 1;
    int rbase = row0 + wr * 64 + (lane & 15);
    int cbase = col0 + wc * 64 + (lane & 15);
    int kg2 = ((lane >> 4) * 8) * 2;        // k-subgroup byte offset
    const char* Ep = (const char*)Eb;
    unsigned aoff[4], boff[4];
#pragma unroll
    for (int i = 0; i < 4; ++i) {
        aoff[i] = (unsigned)min(rbase + i * 16, n - 1) * (ISZ * 2) + kg2;
        boff[i] = (unsigned)min(cbase + i * 16, n - 1) * (ISZ * 2) + kg2;
    }
    f32x4 acc[4][4] = {};
#pragma unroll
    for (int kt = 0; kt < ISZ; kt += 32) {
        bf16x8 a[4], b[4];
#pragma unroll
        for (int i = 0; i < 4; ++i) a[i] = *(const bf16x8*)(Ep + aoff[i] + kt * 2);
#pragma unroll
        for (int j = 0; j < 4; ++j) b[j] = *(const bf16x8*)(Ep + boff[j] + kt * 2);
#pragma unroll
        for (int i = 0; i < 4; ++i)
#pragma unroll
            for (int j = 0; j < 4; ++j)
                acc[i][j] = __builtin_amdgcn_mfma_f32_16x16x32_bf16(a[i], b[j], acc[i][j], 0, 0, 0);
    }
    // C/D layout: col = lane&15, row = (lane>>4)*4 + r  [m89-verified]
    // Stage wave's 64x64 tile in LDS (wave-private: no block barrier needed).
    float (*T)[65] = lds[wid];
#pragma unroll
    for (int i = 0; i < 4; ++i)
#pragma unroll
        for (int j = 0; j < 4; ++j)
#pragma unroll
            for (int r = 0; r < 4; ++r)
                T[(lane >> 4) * 4 + i * 16 + r][(lane & 15) + j * 16] = acc[i][j][r];
    // Coalesced write-out: quad (16 lanes) covers one 64-float row = 256 B.
    int gr0 = row0 + wr * 64;
    int gc0 = col0 + wc * 64;
    int c4 = (lane & 15) * 4;
#pragma unroll
    for (int p = 0; p < 16; ++p) {
        int r = p * 4 + (lane >> 4);
        int gr = gr0 + r;
        if (gr >= n) continue;
        int gc = gc0 + c4;
        float4 w = make_float4(T[r][c4], T[r][c4 + 1], T[r][c4 + 2], T[r][c4 + 3]);
        if (gc + 3 < n) {
            *(float4*)&S[(size_t)gr * n + gc] = w;
        } else {
            float wa[4] = {w.x, w.y, w.z, w.w};
#pragma unroll
            for (int q = 0; q < 4; ++q)
                if (gc + q < n) S[(size_t)gr * n + gc + q] = wa[q];
        }
    }
}

// Round-15 topk (proven) + stored-fp32-rank prefilter: fp64 recompute only the
// stored-top-NSEL candidates (superset of true top-31: fp32 sim err ~1e-4,
// density near rank-31 ~2.4/1e-3 -> only ~5 knife-edge elements; same CMIN=64
// margin round 8 validated). Prefilter placement selc[rank]=c is bijective ->
// deterministic, no atomics.
template <bool PATCHONLY>
__global__ __launch_bounds__(256) void topk_mask(const float* SIM, float* OUT,
                                                 const float* __restrict__ F,
                                                 const float* __restrict__ W0,
                                                 const float* __restrict__ W1,
                                                 const double* __restrict__ snorm,
                                                 int n) {
    __shared__ unsigned flags[320];   // 10000-bit keep mask (legacy mode only)
    __shared__ float redf[8];
    __shared__ int redi[4];
    __shared__ int cand_idx[NCAND];
    __shared__ float csim[NCAND];
    __shared__ int selc[NSEL];
    __shared__ double cand_val[NSEL];
    __shared__ int rankarr[NSEL];
    __shared__ int ncand;
    __shared__ float thr_sh;
    int row = blockIdx.x;
    int tid = threadIdx.x;
    int lane = tid & 63, wid = tid >> 6;
    const float* simp = SIM + (size_t)row * n;
    float* outp = OUT + (size_t)row * n;

    // ---- load row into registers (coalesced float4) ----
    float v[40];
#pragma unroll
    for (int s = 0; s < 10; ++s) {
        int e = 4 * tid + 1024 * s;
        if (e < n) {
            float4 w = *(const float4*)(simp + e);
            v[s * 4 + 0] = w.x; v[s * 4 + 1] = w.y;
            v[s * 4 + 2] = w.z; v[s * 4 + 3] = w.w;
        } else {
#pragma unroll
            for (int q = 0; q < 4; ++q) v[s * 4 + q] = -1e30f;
        }
    }
    if constexpr (!PATCHONLY)
        for (int q = tid; q < 320; q += 256) flags[q] = 0;
    if (tid == 0) ncand = 0;
    __syncthreads();

    // ---- row stats (valid elements only) ----
    {
        float s1 = 0.0f, s2 = 0.0f;
#pragma unroll
        for (int s = 0; s < 10; ++s) {
            int e = 4 * tid + 1024 * s;
            if (e < n) {
#pragma unroll
                for (int j = 0; j < 4; ++j) {
                    float x = v[s * 4 + j];
                    s1 += x;
                    s2 += x * x;
                }
            }
        }
#pragma unroll
        for (int off = 32; off; off >>= 1) {
            s1 += __shfl_down(s1, off);
            s2 += __shfl_down(s2, off);
        }
        if (lane == 0) { redf[wid] = s1; redf[wid + 4] = s2; }
        __syncthreads();
        if (tid == 0) {
            float S1 = redf[0] + redf[1] + redf[2] + redf[3];
            float S2 = redf[4] + redf[5] + redf[6] + redf[7];
            float mean = S1 / (float)n;
            float var = fmaxf(S2 / (float)n - mean * mean, 1e-12f);
            thr_sh = mean + ZSTAT * sqrtf(var);
        }
        __syncthreads();
    }
    float thr = thr_sh;

    auto blockcount = [&](float t) -> int {
        int c = 0;
#pragma unroll
        for (int q = 0; q < 40; ++q) c += (v[q] >= t) ? 1 : 0;
#pragma unroll
        for (int off = 32; off; off >>= 1) c += __shfl_down(c, off);
        if (lane == 0) redi[wid] = c;
        __syncthreads();
        int tot = redi[0] + redi[1] + redi[2] + redi[3];
        __syncthreads();
        return tot;
    };

    auto collect = [&](float t) {
#pragma unroll
        for (int s = 0; s < 10; ++s) {
            int e = 4 * tid + 1024 * s;
#pragma unroll
            for (int j = 0; j < 4; ++j) {
                float x = v[s * 4 + j];
                if (x >= t) {
                    int pos = atomicAdd(&ncand, 1);
                    if (pos < NCAND) { cand_idx[pos] = e + j; csim[pos] = x; }
                }
            }
        }
        __syncthreads();
    };

    collect(thr);
    if (ncand < CMIN || ncand > NCAND) {
        // ---- fallback: verbatim round-8 bisection ----
        __syncthreads();
        if (tid == 0) ncand = 0;
        __syncthreads();
        float lo = 0.0f, hi = 0.75f;
        thr = 0.0f;
        bool found = false;
        for (int it = 0; it < 30 && !found; ++it) {
            float mid = 0.5f * (lo + hi);
            int c = blockcount(mid);
            if (c >= CMIN && c <= CEXIT) { thr = mid; found = true; }
            else if (c >= CMIN) lo = mid;
            else hi = mid;
        }
        if (!found) thr = lo;
        collect(thr);
    }
    int m = min(ncand, NCAND);

    // ---- stored-fp32 lex rank -> top-NSEL prefilter (bijective placement) ----
    for (int c = tid; c < m; c += 256) {
        float mys = csim[c]; int myi = cand_idx[c]; int r = 0;
        for (int j = 0; j < m; ++j) {
            float vj = csim[j];
            r += (vj > mys || (vj == mys && cand_idx[j] < myi)) ? 1 : 0;
        }
        if (r < NSEL) selc[r] = c;
    }
    __syncthreads();
    int mm = min(m, NSEL);

    // ---- fp64 recompute of selected, 4 candidates/iter x 4 waves ----
    double hr[4];
    float w0e[4], w1e[4];
#pragma unroll
    for (int r = 0; r < 4; ++r) {
        int e = lane + 64 * r;
        w0e[r] = W0[e];
        w1e[r] = W1[e];
        hr[r] = h64_of(F[(size_t)row * ISZ + e], w0e[r], w1e[r]);
    }
    double srow = snorm[row];
    for (int s = wid * 4; s < mm; s += 16) {
        int j0 = cand_idx[selc[s]];
        int j1 = cand_idx[selc[min(s + 1, mm - 1)]];
        int j2 = cand_idx[selc[min(s + 2, mm - 1)]];
        int j3 = cand_idx[selc[min(s + 3, mm - 1)]];
        double a0 = 0.0, a1 = 0.0, a2 = 0.0, a3 = 0.0;
#pragma unroll
        for (int r = 0; r < 4; ++r) {
            int e = lane + 64 * r;
            float f0 = F[(size_t)j0 * ISZ + e];
            float f1 = F[(size_t)j1 * ISZ + e];
            float f2 = F[(size_t)j2 * ISZ + e];
            float f3 = F[(size_t)j3 * ISZ + e];
            a0 += hr[r] * h64_of(f0, w0e[r], w1e[r]);
            a1 += hr[r] * h64_of(f1, w0e[r], w1e[r]);
            a2 += hr[r] * h64_of(f2, w0e[r], w1e[r]);
            a3 += hr[r] * h64_of(f3, w0e[r], w1e[r]);
        }
#pragma unroll
        for (int off = 32; off; off >>= 1) {
            a0 += __shfl_down(a0, off);
            a1 += __shfl_down(a1, off);
            a2 += __shfl_down(a2, off);
            a3 += __shfl_down(a3, off);
        }
        if (lane == 0) {
            cand_val[s] = a0 / (srow * snorm[j0]);
            if (s + 1 < mm) cand_val[s + 1] = a1 / (srow * snorm[j1]);
            if (s + 2 < mm) cand_val[s + 2] = a2 / (srow * snorm[j2]);
            if (s + 3 < mm) cand_val[s + 3] = a3 / (srow * snorm[j3]);
        }
    }
    __syncthreads();

    // ---- exact top-KSEL rank among selected (stable lowest-index ties) ----
    for (int s2 = tid; s2 < mm; s2 += 256) {
        double vv = cand_val[s2];
        int idx = cand_idx[selc[s2]];
        int rank = 0;
        for (int j2 = 0; j2 < mm; ++j2) {
            double vj = cand_val[j2];
            rank += (vj > vv || (vj == vv && cand_idx[selc[j2]] < idx)) ? 1 : 0;
        }
        rankarr[s2] = rank;
        if constexpr (!PATCHONLY) {
            if (rank < KSEL) atomicOr(&flags[idx >> 5], 1u << (idx & 31));
        }
    }
    __syncthreads();

    if constexpr (!PATCHONLY) {
        // ---- masked relu rewrite from registers ----
#pragma unroll
        for (int s = 0; s < 10; ++s) {
            int e = 4 * tid + 1024 * s;
            if (e >= n) continue;
            float vals[4] = {v[s * 4 + 0], v[s * 4 + 1], v[s * 4 + 2], v[s * 4 + 3]};
            float o[4];
#pragma unroll
            for (int j = 0; j < 4; ++j) {
                int q = e + j;
                bool keep = (flags[q >> 5] >> (q & 31)) & 1u;
                o[j] = (keep && vals[j] > 0.0f) ? vals[j] : 0.0f;
            }
            *(float4*)(outp + e) = make_float4(o[0], o[1], o[2], o[3]);
        }
        __syncthreads();   // order bulk writes before the patch
    }

    // ---- fp64 value patch of kept entries ----
    for (int s2 = tid; s2 < mm; s2 += 256) {
        if (rankarr[s2] < KSEL)
            outp[cand_idx[selc[s2]]] = (float)fmax(cand_val[s2], 0.0);
    }
}

extern "C" void kernel_launch(void* const* d_in, const int* in_sizes, int n_in,
                              void* d_out, int out_size, void* d_ws, size_t ws_size,
                              hipStream_t stream) {
    const float* F  = (const float*)d_in[0];
    const float* w0 = (const float*)d_in[1];
    const float* w1 = (const float*)d_in[2];
    float* out = (float*)d_out;
    int isz = in_sizes[1];           // 256
    int n = in_sizes[0] / isz;       // 10000

    char* ws = (char*)d_ws;
    __hip_bfloat16* Ebf = (__hip_bfloat16*)ws;                       // 5.12 MB
    double* snorm = (double*)(ws + (size_t)n * ISZ * 2);             // 80 KB
    size_t o_sim = (((size_t)n * ISZ * 2 + (size_t)n * 8) + 255) & ~(size_t)255;
    size_t need = o_sim + (size_t)n * n * 4;                         // +400 MB

    int nt = (n + 127) / 128;
    emb_kernel<<<n, 256, 0, stream>>>(F, w0, w1, Ebf, snorm, n);
    if (ws_size >= need) {
        float* S = (float*)(ws + o_sim);
        hipMemsetAsync(d_out, 0, (size_t)n * n * sizeof(float), stream);
        gemm_mfma<<<dim3(nt, nt), 256, 0, stream>>>(Ebf, S, n);
        topk_mask<true><<<n, 256, 0, stream>>>(S, out, F, w0, w1, snorm, n);
    } else {
        gemm_mfma<<<dim3(nt, nt), 256, 0, stream>>>(Ebf, out, n);
        topk_mask<false><<<n, 256, 0, stream>>>(out, out, F, w0, w1, snorm, n);
    }
}

// Round 17
// 543.715 us; speedup vs baseline: 1.8070x; 1.0140x over previous
//
#include <hip/hip_runtime.h>
#include <hip/hip_bf16.h>
#include <math.h>

#define ISZ 256
#define KSEL 31      // keep top-(K+1) = 31
#define CMIN 64      // min candidate count (margin over KSEL for bf16-GEMM error)
#define CEXIT 192    // bisection-fallback early-exit upper bound
#define NCAND 320    // candidate buffer cap
#define NSEL 64      // stored-rank prefilter size (superset of true top-31)
#define ZSTAT 2.25f  // thr = mean + ZSTAT*sd (~120 cands)

typedef __attribute__((ext_vector_type(8))) short bf16x8;
typedef __attribute__((ext_vector_type(4))) float f32x4;

__device__ __forceinline__ double h64_of(float f, float w0, float w1) {
    return fmax((double)f * (double)w0, 0.0) * (double)w1;
}

// Eb = bf16 normalized embedding; snorm = fp64 ||h||. (round-8 proven, verbatim)
__global__ __launch_bounds__(256) void emb_kernel(const float* __restrict__ F,
                                                  const float* __restrict__ w0,
                                                  const float* __restrict__ w1,
                                                  __hip_bfloat16* __restrict__ Eb,
                                                  double* __restrict__ snorm,
                                                  int n) {
    int row = blockIdx.x;
    int t = threadIdx.x;
    float f = F[(size_t)row * ISZ + t];
    double h64 = h64_of(f, w0[t], w1[t]);
    double ss = h64 * h64;
#pragma unroll
    for (int off = 32; off; off >>= 1) ss += __shfl_down(ss, off);
    __shared__ double red[4];
    if ((t & 63) == 0) red[t >> 6] = ss;
    __syncthreads();
    double tot = red[0] + red[1] + red[2] + red[3];
    double s = fmax(sqrt(tot), 1e-12);
    if (t == 0) snorm[row] = s;
    Eb[(size_t)row * ISZ + t] = __float2bfloat16((float)(h64 / s));
}

// Symmetric S = Eb*Eb^T: only bx>=by tiles computed (half the MFMA work).
// R16-proven MFMA core + LDS-staged epilogue; mirror tile written from the
// SAME LDS tile via transposed reads -> both writes coalesced. Epilogue also
// accumulates per-row sum/sumsq (fp32 atomics) for the topk threshold.
__global__ __launch_bounds__(256) void gemm_mfma(const __hip_bfloat16* __restrict__ Eb,
                                                 float* __restrict__ S,
                                                 float* __restrict__ rsum,
                                                 float* __restrict__ rsumsq,
                                                 int n) {
    int bx = blockIdx.x, by = blockIdx.y;
    if (bx < by) return;
    __shared__ float lds[4][64][65];
    int row0 = by * 128, col0 = bx * 128;
    int tid = threadIdx.x, lane = tid & 63, wid = tid >> 6;
    int wr = wid >> 1, wc = wid & 1;
    int rbase = row0 + wr * 64 + (lane & 15);
    int cbase = col0 + wc * 64 + (lane & 15);
    int kg2 = ((lane >> 4) * 8) * 2;        // k-subgroup byte offset
    const char* Ep = (const char*)Eb;
    unsigned aoff[4], boff[4];
#pragma unroll
    for (int i = 0; i < 4; ++i) {
        aoff[i] = (unsigned)min(rbase + i * 16, n - 1) * (ISZ * 2) + kg2;
        boff[i] = (unsigned)min(cbase + i * 16, n - 1) * (ISZ * 2) + kg2;
    }
    f32x4 acc[4][4] = {};
#pragma unroll
    for (int kt = 0; kt < ISZ; kt += 32) {
        bf16x8 a[4], b[4];
#pragma unroll
        for (int i = 0; i < 4; ++i) a[i] = *(const bf16x8*)(Ep + aoff[i] + kt * 2);
#pragma unroll
        for (int j = 0; j < 4; ++j) b[j] = *(const bf16x8*)(Ep + boff[j] + kt * 2);
#pragma unroll
        for (int i = 0; i < 4; ++i)
#pragma unroll
            for (int j = 0; j < 4; ++j)
                acc[i][j] = __builtin_amdgcn_mfma_f32_16x16x32_bf16(a[i], b[j], acc[i][j], 0, 0, 0);
    }
    // C/D layout: col = lane&15, row = (lane>>4)*4 + r  [m89-verified]
    float (*T)[65] = lds[wid];   // wave-private 64x64 subtile, no barriers
#pragma unroll
    for (int i = 0; i < 4; ++i)
#pragma unroll
        for (int j = 0; j < 4; ++j)
#pragma unroll
            for (int r = 0; r < 4; ++r)
                T[(lane >> 4) * 4 + i * 16 + r][(lane & 15) + j * 16] = acc[i][j][r];
    int gr0 = row0 + wr * 64;
    int gc0 = col0 + wc * 64;
    int c4 = (lane & 15) * 4;
    // ---- (by,bx) tile: quad writes one 64-float row segment (256 B) ----
#pragma unroll
    for (int p = 0; p < 16; ++p) {
        int r = p * 4 + (lane >> 4);
        int gr = gr0 + r;
        if (gr >= n) continue;
        int gc = gc0 + c4;
        float4 w = make_float4(T[r][c4], T[r][c4 + 1], T[r][c4 + 2], T[r][c4 + 3]);
        if (gc + 3 < n) {
            *(float4*)&S[(size_t)gr * n + gc] = w;
        } else {
            float wa[4] = {w.x, w.y, w.z, w.w};
#pragma unroll
            for (int q = 0; q < 4; ++q)
                if (gc + q < n) S[(size_t)gr * n + gc + q] = wa[q];
        }
    }
    // ---- row stats for (by,bx): lane owns subtile row r=lane ----
    {
        int gr = gr0 + lane;
        if (gr < n) {
            float s1 = 0.0f, s2 = 0.0f;
            int cmax = min(64, n - gc0);
            for (int c = 0; c < cmax; ++c) {
                float x = T[lane][c];
                s1 += x; s2 += x * x;
            }
            if (cmax > 0) { atomicAdd(&rsum[gr], s1); atomicAdd(&rsumsq[gr], s2); }
        }
    }
    if (bx > by) {
        // ---- mirror tile (bx,by): transposed LDS reads, coalesced stores ----
#pragma unroll
        for (int p = 0; p < 16; ++p) {
            int rp = p * 4 + (lane >> 4);      // mirror row offset = orig col
            int gr2 = gc0 + rp;
            if (gr2 >= n) continue;
            int gc2 = gr0 + c4;
            float4 w = make_float4(T[c4][rp], T[c4 + 1][rp], T[c4 + 2][rp], T[c4 + 3][rp]);
            if (gc2 + 3 < n) {
                *(float4*)&S[(size_t)gr2 * n + gc2] = w;
            } else {
                float wa[4] = {w.x, w.y, w.z, w.w};
#pragma unroll
                for (int q = 0; q < 4; ++q)
                    if (gc2 + q < n) S[(size_t)gr2 * n + gc2 + q] = wa[q];
            }
        }
        // ---- mirror row stats: lane owns subtile col c=lane ----
        int gr2 = gc0 + lane;
        if (gr2 < n) {
            float s1 = 0.0f, s2 = 0.0f;
            int rmax = min(64, n - gr0);
            for (int r = 0; r < rmax; ++r) {
                float x = T[r][lane];
                s1 += x; s2 += x * x;
            }
            if (rmax > 0) { atomicAdd(&rsum[gr2], s1); atomicAdd(&rsumsq[gr2], s2); }
        }
    }
}

// Streaming topk (big-ws path): thr from precomputed row stats; single fused
// load+collect pass (no register row residency); candidate phases verbatim
// from round 16 (prefilter -> fp64 -> rank -> patch; d_out pre-zeroed).
// Replay determinism: output = f(top-NSEL by (stored,idx) among any candidate
// superset with count>=CMIN) — invariant to ulp-level thr wiggle from atomic
// fp32 stat accumulation; out-of-window rows take a deterministic bisection.
__global__ __launch_bounds__(256) void topk_stream(const float* __restrict__ SIM,
                                                   float* __restrict__ OUT,
                                                   const float* __restrict__ F,
                                                   const float* __restrict__ W0,
                                                   const float* __restrict__ W1,
                                                   const double* __restrict__ snorm,
                                                   const float* __restrict__ rsum,
                                                   const float* __restrict__ rsumsq,
                                                   int n) {
    __shared__ int redi[4];
    __shared__ int cand_idx[NCAND];
    __shared__ float csim[NCAND];
    __shared__ int selc[NSEL];
    __shared__ double cand_val[NSEL];
    __shared__ int rankarr[NSEL];
    __shared__ int ncand;
    int row = blockIdx.x;
    int tid = threadIdx.x;
    int lane = tid & 63, wid = tid >> 6;
    const float* simp = SIM + (size_t)row * n;
    float* outp = OUT + (size_t)row * n;

    float mean = rsum[row] / (float)n;
    float var = fmaxf(rsumsq[row] / (float)n - mean * mean, 1e-12f);
    float thr = mean + ZSTAT * sqrtf(var);
    if (tid == 0) ncand = 0;
    __syncthreads();

    // ---- fused streaming load + collect ----
#pragma unroll
    for (int s = 0; s < 10; ++s) {
        int e = 4 * tid + 1024 * s;
        if (e < n) {
            float4 w = *(const float4*)(simp + e);
            float wa[4] = {w.x, w.y, w.z, w.w};
#pragma unroll
            for (int j = 0; j < 4; ++j) {
                if (wa[j] >= thr) {
                    int pos = atomicAdd(&ncand, 1);
                    if (pos < NCAND) { cand_idx[pos] = e + j; csim[pos] = wa[j]; }
                }
            }
        }
    }
    __syncthreads();

    if (ncand < CMIN || ncand > NCAND) {
        // ---- rare fallback: streaming bisection (row is L2-hot) ----
        auto bcount = [&](float t) -> int {
            int c = 0;
#pragma unroll
            for (int s = 0; s < 10; ++s) {
                int e = 4 * tid + 1024 * s;
                if (e < n) {
                    float4 w = *(const float4*)(simp + e);
                    c += (w.x >= t) + (w.y >= t) + (w.z >= t) + (w.w >= t);
                }
            }
#pragma unroll
            for (int off = 32; off; off >>= 1) c += __shfl_down(c, off);
            if (lane == 0) redi[wid] = c;
            __syncthreads();
            int tot = redi[0] + redi[1] + redi[2] + redi[3];
            __syncthreads();
            return tot;
        };
        __syncthreads();
        if (tid == 0) ncand = 0;
        __syncthreads();
        float lo = 0.0f, hi = 0.75f;
        thr = 0.0f;
        bool found = false;
        for (int it = 0; it < 30 && !found; ++it) {
            float mid = 0.5f * (lo + hi);
            int c = bcount(mid);
            if (c >= CMIN && c <= CEXIT) { thr = mid; found = true; }
            else if (c >= CMIN) lo = mid;
            else hi = mid;
        }
        if (!found) thr = lo;
#pragma unroll
        for (int s = 0; s < 10; ++s) {
            int e = 4 * tid + 1024 * s;
            if (e < n) {
                float4 w = *(const float4*)(simp + e);
                float wa[4] = {w.x, w.y, w.z, w.w};
#pragma unroll
                for (int j = 0; j < 4; ++j) {
                    if (wa[j] >= thr) {
                        int pos = atomicAdd(&ncand, 1);
                        if (pos < NCAND) { cand_idx[pos] = e + j; csim[pos] = wa[j]; }
                    }
                }
            }
        }
        __syncthreads();
    }
    int m = min(ncand, NCAND);

    // ---- stored-fp32 lex rank -> top-NSEL prefilter (bijective placement) ----
    for (int c = tid; c < m; c += 256) {
        float mys = csim[c]; int myi = cand_idx[c]; int r = 0;
        for (int j = 0; j < m; ++j) {
            float vj = csim[j];
            r += (vj > mys || (vj == mys && cand_idx[j] < myi)) ? 1 : 0;
        }
        if (r < NSEL) selc[r] = c;
    }
    __syncthreads();
    int mm = min(m, NSEL);

    // ---- fp64 recompute of selected, 4 candidates/iter x 4 waves ----
    double hr[4];
    float w0e[4], w1e[4];
#pragma unroll
    for (int r = 0; r < 4; ++r) {
        int e = lane + 64 * r;
        w0e[r] = W0[e];
        w1e[r] = W1[e];
        hr[r] = h64_of(F[(size_t)row * ISZ + e], w0e[r], w1e[r]);
    }
    double srow = snorm[row];
    for (int s = wid * 4; s < mm; s += 16) {
        int j0 = cand_idx[selc[s]];
        int j1 = cand_idx[selc[min(s + 1, mm - 1)]];
        int j2 = cand_idx[selc[min(s + 2, mm - 1)]];
        int j3 = cand_idx[selc[min(s + 3, mm - 1)]];
        double a0 = 0.0, a1 = 0.0, a2 = 0.0, a3 = 0.0;
#pragma unroll
        for (int r = 0; r < 4; ++r) {
            int e = lane + 64 * r;
            float f0 = F[(size_t)j0 * ISZ + e];
            float f1 = F[(size_t)j1 * ISZ + e];
            float f2 = F[(size_t)j2 * ISZ + e];
            float f3 = F[(size_t)j3 * ISZ + e];
            a0 += hr[r] * h64_of(f0, w0e[r], w1e[r]);
            a1 += hr[r] * h64_of(f1, w0e[r], w1e[r]);
            a2 += hr[r] * h64_of(f2, w0e[r], w1e[r]);
            a3 += hr[r] * h64_of(f3, w0e[r], w1e[r]);
        }
#pragma unroll
        for (int off = 32; off; off >>= 1) {
            a0 += __shfl_down(a0, off);
            a1 += __shfl_down(a1, off);
            a2 += __shfl_down(a2, off);
            a3 += __shfl_down(a3, off);
        }
        if (lane == 0) {
            cand_val[s] = a0 / (srow * snorm[j0]);
            if (s + 1 < mm) cand_val[s + 1] = a1 / (srow * snorm[j1]);
            if (s + 2 < mm) cand_val[s + 2] = a2 / (srow * snorm[j2]);
            if (s + 3 < mm) cand_val[s + 3] = a3 / (srow * snorm[j3]);
        }
    }
    __syncthreads();

    // ---- exact top-KSEL rank among selected (stable lowest-index ties) ----
    for (int s2 = tid; s2 < mm; s2 += 256) {
        double vv = cand_val[s2];
        int idx = cand_idx[selc[s2]];
        int rank = 0;
        for (int j2 = 0; j2 < mm; ++j2) {
            double vj = cand_val[j2];
            rank += (vj > vv || (vj == vv && cand_idx[selc[j2]] < idx)) ? 1 : 0;
        }
        rankarr[s2] = rank;
    }
    __syncthreads();

    // ---- fp64 value patch of kept entries (d_out pre-zeroed by memset) ----
    for (int s2 = tid; s2 < mm; s2 += 256) {
        if (rankarr[s2] < KSEL)
            outp[cand_idx[selc[s2]]] = (float)fmax(cand_val[s2], 0.0);
    }
}

// Legacy small-ws topk (round-16 <false> path, verbatim structure): sims in
// d_out, in-kernel stats + bulk masked rewrite.
__global__ __launch_bounds__(256) void topk_legacy(float* C,
                                                   const float* __restrict__ F,
                                                   const float* __restrict__ W0,
                                                   const float* __restrict__ W1,
                                                   const double* __restrict__ snorm,
                                                   int n) {
    __shared__ unsigned flags[320];
    __shared__ float redf[8];
    __shared__ int redi[4];
    __shared__ int cand_idx[NCAND];
    __shared__ float csim[NCAND];
    __shared__ int selc[NSEL];
    __shared__ double cand_val[NSEL];
    __shared__ int rankarr[NSEL];
    __shared__ int ncand;
    __shared__ float thr_sh;
    int row = blockIdx.x;
    int tid = threadIdx.x;
    int lane = tid & 63, wid = tid >> 6;
    float* rowp = C + (size_t)row * n;
    float v[40];
#pragma unroll
    for (int s = 0; s < 10; ++s) {
        int e = 4 * tid + 1024 * s;
        if (e < n) {
            float4 w = *(const float4*)(rowp + e);
            v[s * 4 + 0] = w.x; v[s * 4 + 1] = w.y;
            v[s * 4 + 2] = w.z; v[s * 4 + 3] = w.w;
        } else {
#pragma unroll
            for (int q = 0; q < 4; ++q) v[s * 4 + q] = -1e30f;
        }
    }
    for (int q = tid; q < 320; q += 256) flags[q] = 0;
    if (tid == 0) ncand = 0;
    __syncthreads();
    {
        float s1 = 0.0f, s2 = 0.0f;
#pragma unroll
        for (int s = 0; s < 10; ++s) {
            int e = 4 * tid + 1024 * s;
            if (e < n) {
#pragma unroll
                for (int j = 0; j < 4; ++j) { float x = v[s * 4 + j]; s1 += x; s2 += x * x; }
            }
        }
#pragma unroll
        for (int off = 32; off; off >>= 1) { s1 += __shfl_down(s1, off); s2 += __shfl_down(s2, off); }
        if (lane == 0) { redf[wid] = s1; redf[wid + 4] = s2; }
        __syncthreads();
        if (tid == 0) {
            float S1 = redf[0] + redf[1] + redf[2] + redf[3];
            float S2 = redf[4] + redf[5] + redf[6] + redf[7];
            float mean = S1 / (float)n;
            float var = fmaxf(S2 / (float)n - mean * mean, 1e-12f);
            thr_sh = mean + ZSTAT * sqrtf(var);
        }
        __syncthreads();
    }
    float thr = thr_sh;
    auto blockcount = [&](float t) -> int {
        int c = 0;
#pragma unroll
        for (int q = 0; q < 40; ++q) c += (v[q] >= t) ? 1 : 0;
#pragma unroll
        for (int off = 32; off; off >>= 1) c += __shfl_down(c, off);
        if (lane == 0) redi[wid] = c;
        __syncthreads();
        int tot = redi[0] + redi[1] + redi[2] + redi[3];
        __syncthreads();
        return tot;
    };
    auto collect = [&](float t) {
#pragma unroll
        for (int s = 0; s < 10; ++s) {
            int e = 4 * tid + 1024 * s;
#pragma unroll
            for (int j = 0; j < 4; ++j) {
                float x = v[s * 4 + j];
                if (x >= t) {
                    int pos = atomicAdd(&ncand, 1);
                    if (pos < NCAND) { cand_idx[pos] = e + j; csim[pos] = x; }
                }
            }
        }
        __syncthreads();
    };
    collect(thr);
    if (ncand < CMIN || ncand > NCAND) {
        __syncthreads();
        if (tid == 0) ncand = 0;
        __syncthreads();
        float lo = 0.0f, hi = 0.75f;
        thr = 0.0f;
        bool found = false;
        for (int it = 0; it < 30 && !found; ++it) {
            float mid = 0.5f * (lo + hi);
            int c = blockcount(mid);
            if (c >= CMIN && c <= CEXIT) { thr = mid; found = true; }
            else if (c >= CMIN) lo = mid;
            else hi = mid;
        }
        if (!found) thr = lo;
        collect(thr);
    }
    int m = min(ncand, NCAND);
    for (int c = tid; c < m; c += 256) {
        float mys = csim[c]; int myi = cand_idx[c]; int r = 0;
        for (int j = 0; j < m; ++j) {
            float vj = csim[j];
            r += (vj > mys || (vj == mys && cand_idx[j] < myi)) ? 1 : 0;
        }
        if (r < NSEL) selc[r] = c;
    }
    __syncthreads();
    int mm = min(m, NSEL);
    double hr[4]; float w0e[4], w1e[4];
#pragma unroll
    for (int r = 0; r < 4; ++r) {
        int e = lane + 64 * r;
        w0e[r] = W0[e]; w1e[r] = W1[e];
        hr[r] = h64_of(F[(size_t)row * ISZ + e], w0e[r], w1e[r]);
    }
    double srow = snorm[row];
    for (int s = wid * 4; s < mm; s += 16) {
        int j0 = cand_idx[selc[s]];
        int j1 = cand_idx[selc[min(s + 1, mm - 1)]];
        int j2 = cand_idx[selc[min(s + 2, mm - 1)]];
        int j3 = cand_idx[selc[min(s + 3, mm - 1)]];
        double a0 = 0.0, a1 = 0.0, a2 = 0.0, a3 = 0.0;
#pragma unroll
        for (int r = 0; r < 4; ++r) {
            int e = lane + 64 * r;
            a0 += hr[r] * h64_of(F[(size_t)j0 * ISZ + e], w0e[r], w1e[r]);
            a1 += hr[r] * h64_of(F[(size_t)j1 * ISZ + e], w0e[r], w1e[r]);
            a2 += hr[r] * h64_of(F[(size_t)j2 * ISZ + e], w0e[r], w1e[r]);
            a3 += hr[r] * h64_of(F[(size_t)j3 * ISZ + e], w0e[r], w1e[r]);
        }
#pragma unroll
        for (int off = 32; off; off >>= 1) {
            a0 += __shfl_down(a0, off); a1 += __shfl_down(a1, off);
            a2 += __shfl_down(a2, off); a3 += __shfl_down(a3, off);
        }
        if (lane == 0) {
            cand_val[s] = a0 / (srow * snorm[j0]);
            if (s + 1 < mm) cand_val[s + 1] = a1 / (srow * snorm[j1]);
            if (s + 2 < mm) cand_val[s + 2] = a2 / (srow * snorm[j2]);
            if (s + 3 < mm) cand_val[s + 3] = a3 / (srow * snorm[j3]);
        }
    }
    __syncthreads();
    for (int s2 = tid; s2 < mm; s2 += 256) {
        double vv = cand_val[s2];
        int idx = cand_idx[selc[s2]];
        int rank = 0;
        for (int j2 = 0; j2 < mm; ++j2) {
            double vj = cand_val[j2];
            rank += (vj > vv || (vj == vv && cand_idx[selc[j2]] < idx)) ? 1 : 0;
        }
        rankarr[s2] = rank;
        if (rank < KSEL) atomicOr(&flags[idx >> 5], 1u << (idx & 31));
    }
    __syncthreads();
#pragma unroll
    for (int s = 0; s < 10; ++s) {
        int e = 4 * tid + 1024 * s;
        if (e >= n) continue;
        float vals[4] = {v[s * 4 + 0], v[s * 4 + 1], v[s * 4 + 2], v[s * 4 + 3]};
        float o[4];
#pragma unroll
        for (int j = 0; j < 4; ++j) {
            int q = e + j;
            bool keep = (flags[q >> 5] >> (q & 31)) & 1u;
            o[j] = (keep && vals[j] > 0.0f) ? vals[j] : 0.0f;
        }
        *(float4*)(rowp + e) = make_float4(o[0], o[1], o[2], o[3]);
    }
    __syncthreads();
    for (int s2 = tid; s2 < mm; s2 += 256) {
        if (rankarr[s2] < KSEL)
            rowp[cand_idx[selc[s2]]] = (float)fmax(cand_val[s2], 0.0);
    }
}

extern "C" void kernel_launch(void* const* d_in, const int* in_sizes, int n_in,
                              void* d_out, int out_size, void* d_ws, size_t ws_size,
                              hipStream_t stream) {
    const float* F  = (const float*)d_in[0];
    const float* w0 = (const float*)d_in[1];
    const float* w1 = (const float*)d_in[2];
    float* out = (float*)d_out;
    int isz = in_sizes[1];           // 256
    int n = in_sizes[0] / isz;       // 10000

    char* ws = (char*)d_ws;
    __hip_bfloat16* Ebf = (__hip_bfloat16*)ws;                       // 5.12 MB
    size_t o_snorm = (size_t)n * ISZ * 2;
    double* snorm = (double*)(ws + o_snorm);                         // 80 KB
    size_t o_rsum = o_snorm + (size_t)n * 8;
    float* rsum = (float*)(ws + o_rsum);                             // 40 KB
    float* rsumsq = (float*)(ws + o_rsum + (size_t)n * 4);           // 40 KB
    size_t o_sim = (o_rsum + (size_t)n * 8 + 255) & ~(size_t)255;
    size_t need = o_sim + (size_t)n * n * 4;                         // +400 MB

    int nt = (n + 127) / 128;
    emb_kernel<<<n, 256, 0, stream>>>(F, w0, w1, Ebf, snorm, n);
    hipMemsetAsync(rsum, 0, (size_t)n * 8, stream);
    if (ws_size >= need) {
        float* S = (float*)(ws + o_sim);
        hipMemsetAsync(d_out, 0, (size_t)n * n * sizeof(float), stream);
        gemm_mfma<<<dim3(nt, nt), 256, 0, stream>>>(Ebf, S, rsum, rsumsq, n);
        topk_stream<<<n, 256, 0, stream>>>(S, out, F, w0, w1, snorm, rsum, rsumsq, n);
    } else {
        gemm_mfma<<<dim3(nt, nt), 256, 0, stream>>>(Ebf, out, rsum, rsumsq, n);
        topk_legacy<<<n, 256, 0, stream>>>(out, F, w0, w1, snorm, n);
    }
}